// Round 15
// baseline (223.491 us; speedup 1.0000x reference)
//
#include <hip/hip_runtime.h>
#include <cstdint>

#define DEVI static __device__ __forceinline__

typedef __attribute__((ext_vector_type(8))) short bf16x8;
typedef __attribute__((ext_vector_type(4))) float f32x4;
typedef __attribute__((ext_vector_type(8))) unsigned short ush8;

DEVI unsigned short f2bf(float f) {
    unsigned u = __float_as_uint(f);
    u += 0x7fff + ((u >> 16) & 1);
    return (unsigned short)(u >> 16);
}
DEVI float bf2f(unsigned short h) { return __uint_as_float(((unsigned)h) << 16); }

DEVI void gload16(const void* g, void* l) {
    __builtin_amdgcn_global_load_lds((const __attribute__((address_space(1))) void*)g,
                                     (__attribute__((address_space(3))) void*)l, 16, 0, 0);
}

DEVI float fast_gelu(float x) {
    // tanh-approx GELU via raw v_rcp_f32 (no -ffast-math; '/' would expand to ~12-op exact div)
    float z = 1.5957691216057308f * (x + 0.044715f * x * x * x);
    return x - x * __builtin_amdgcn_rcpf(__expf(z) + 1.f);
}

// ---------------- weight pack: fp32 -> bf16 in MFMA-fragment order ----------------
__global__ __launch_bounds__(256) void k_pack(const float* __restrict__ Wq, const float* __restrict__ Wkv,
                                              const float* __restrict__ Wp, const float* __restrict__ Wf1,
                                              const float* __restrict__ Wf2, unsigned short* __restrict__ dst) {
    int t = blockIdx.x * 256 + threadIdx.x;
    if (t >= 55296) return;
    int c, base, K;
    const float* src = nullptr;
    if (t < 13824)      { c = t;         base = 0;      K = 192; }
    else if (t < 18432) { c = t - 13824; base = 110592; K = 192; src = Wp; }
    else if (t < 36864) { c = t - 18432; base = 147456; K = 192; src = Wf1; }
    else                { c = t - 36864; base = 294912; K = 768; src = Wf2; }
    int lane = c & 63, fk = c >> 6, Kf = K >> 5;
    int kf = fk % Kf, nf = fk / Kf;
    int row = nf * 16 + (lane & 15), col = kf * 32 + (lane >> 4) * 8;
    ush8 o;
    if (t < 13824) {
        if (row < 192) {
            #pragma unroll
            for (int q = 0; q < 8; q++) o[q] = f2bf(Wq[row * 192 + col + q] * 0.17677669529663687f);
        } else {
            #pragma unroll
            for (int q = 0; q < 8; q++) o[q] = f2bf(Wkv[(row - 192) * 192 + col + q]);
        }
    } else {
        #pragma unroll
        for (int q = 0; q < 8; q++) o[q] = f2bf(src[(long)row * K + col + q]);
    }
    *(ush8*)&dst[base + c * 8] = o;
}

// ---------------- fused bias+mask table: [6 heads][8 variants][128 i][16 li][8 fn] f32 ----------------
__global__ __launch_bounds__(256) void k_bmt(const float* __restrict__ rpb, float* __restrict__ bmt) {
    int t = blockIdx.x * 256 + threadIdx.x;  // 6 * 131072
    int h = t >> 17;
    int r = t & 131071;
    int v = r >> 14;
    int ij = r & 16383;
    int i = ij >> 7, li = (ij >> 3) & 15, fn = ij & 7;
    int j = fn * 16 + li;
    int tdi = i >> 6, thi = (i >> 3) & 7, twi = i & 7;
    int tdj = j >> 6, thj = (j >> 3) & 7, twj = j & 7;
    int idx = ((tdi - tdj + 1) * 15 + (thi - thj + 7)) * 15 + (twi - twj + 7);
    float b = rpb[idx * 6 + h];
    int dwb = v & 1, hwb = (v >> 1) & 1, wwb = (v >> 2) & 1;
    int ri = (dwb ? 1 + tdi : 0) * 9 + (hwb ? (thi < 4 ? 1 : 2) : 0) * 3 + (wwb ? (twi < 4 ? 1 : 2) : 0);
    int rj = (dwb ? 1 + tdj : 0) * 9 + (hwb ? (thj < 4 ? 1 : 2) : 0) * 3 + (wwb ? (twj < 4 ? 1 : 2) : 0);
    if (ri != rj) b -= 100.f;
    bmt[(long)(h * 8 + v) * 16384 + i * 128 + li * 8 + fn] = b;
}

// ---------------- LayerNorm fused with roll+window gather ----------------
__global__ __launch_bounds__(256) void k_ln(const float* __restrict__ x, const float* __restrict__ g,
                                            const float* __restrict__ b, unsigned short* __restrict__ outp) {
    int wid = threadIdx.x >> 6, lane = threadIdx.x & 63;
    int t = blockIdx.x * 4 + wid;
    int w = t >> 7, tt = t & 127;
    int bb = w >> 8, rem = w & 255;
    int dw = rem >> 6, hw = (rem >> 3) & 7, ww = rem & 7;
    int td = tt >> 6, th = (tt >> 3) & 7, tw = tt & 7;
    int d = (dw * 2 + td + 1) & 7;
    int hh = (hw * 8 + th + 4) & 63;
    int wo = (ww * 8 + tw + 4) & 63;
    long src = (long)((bb * 8 + d) * 64 + hh) * 64 + wo;
    const float* xp = x + src * 192;
    float v0 = xp[lane], v1 = xp[lane + 64], v2 = xp[lane + 128];
    float s = v0 + v1 + v2, ss = v0 * v0 + v1 * v1 + v2 * v2;
    #pragma unroll
    for (int m = 32; m; m >>= 1) { s += __shfl_xor(s, m); ss += __shfl_xor(ss, m); }
    float mu = s * (1.f / 192.f);
    float var = ss * (1.f / 192.f) - mu * mu;
    float inv = rsqrtf(var + 1e-5f);
    unsigned short* op = outp + (long)t * 192;
    op[lane]       = f2bf((v0 - mu) * inv * g[lane]       + b[lane]);
    op[lane + 64]  = f2bf((v1 - mu) * inv * g[lane + 64]  + b[lane + 64]);
    op[lane + 128] = f2bf((v2 - mu) * inv * g[lane + 128] + b[lane + 128]);
}

// ---------------- bf16 MFMA GEMM: C[M,N] = A[M,K] @ B[N,K]^T, B in packed-frag form ----------------
// EPI: 0=QKV scatter (bf16 out), 1=proj + window-reverse + residual -> x1 bf16
template <int EPI>
__global__ __launch_bounds__(256, 4) void k_gemm(const unsigned short* __restrict__ A,
                                                 const unsigned short* __restrict__ Bpk, int K,
                                                 const float* __restrict__ bias,
                                                 const float* __restrict__ addsrc,
                                                 unsigned short* __restrict__ outU) {
    __shared__ __align__(16) unsigned short As[2][256 * 32];
    int tid = threadIdx.x;
    int wid = tid >> 6, lane = tid & 63;
    int g = lane >> 4, li = lane & 15;
    int m0 = blockIdx.y * 256, n0 = blockIdx.x * 64;
    int Kf = K >> 5;

    f32x4 acc[4][4];
    #pragma unroll
    for (int i = 0; i < 4; i++)
        #pragma unroll
        for (int j = 0; j < 4; j++) acc[i][j] = (f32x4){0.f, 0.f, 0.f, 0.f};

    int sg = ((tid & 3) ^ ((tid >> 3) & 3)) * 8;
    const unsigned short* pa = A + (long)(m0 + (tid >> 2)) * K + sg;
    const unsigned short* pbk = Bpk + ((long)(n0 >> 4) * Kf * 64 + lane) * 8;

#define STAGE(buf, kt) do { \
    _Pragma("unroll") \
    for (int c = 0; c < 4; c++) \
        gload16(pa + (long)(c * 64) * K + (kt), &As[buf][c * 2048 + tid * 8]); \
} while (0)

    STAGE(0, 0);
    __syncthreads();

    int cur = 0;
    int acol = (g ^ ((li >> 1) & 3)) * 8;
    for (int t = 0; t < Kf; t++) {
        bf16x8 bfr[4];
        #pragma unroll
        for (int j = 0; j < 4; j++)
            bfr[j] = *(const bf16x8*)(pbk + ((long)j * Kf + t) * 512);
        if (t + 1 < Kf) STAGE(cur ^ 1, (t + 1) << 5);
        const unsigned short* ab = &As[cur][(wid * 64 + li) * 32 + acol];
        bf16x8 af[4];
        #pragma unroll
        for (int i = 0; i < 4; i++) af[i] = *(const bf16x8*)(ab + i * 512);
        __builtin_amdgcn_s_setprio(1);
        #pragma unroll
        for (int i = 0; i < 4; i++)
            #pragma unroll
            for (int j = 0; j < 4; j++)
                acc[i][j] = __builtin_amdgcn_mfma_f32_16x16x32_bf16(af[i], bfr[j], acc[i][j], 0, 0, 0);
        __builtin_amdgcn_s_setprio(0);
        if (t + 1 < Kf) {
            __syncthreads();
            cur ^= 1;
        }
    }
#undef STAGE

    #pragma unroll
    for (int i = 0; i < 4; i++) {
        int rowb = m0 + wid * 64 + i * 16 + g * 4;
        #pragma unroll
        for (int j = 0; j < 4; j++) {
            int col = n0 + j * 16 + li;
            #pragma unroll
            for (int r = 0; r < 4; r++) {
                float v = acc[i][j][r];
                int rr = rowb + r;
                if (EPI == 0) {
                    int sec = col / 192;
                    int cc = col - sec * 192;
                    int h = cc >> 5, d = cc & 31;
                    int w = rr >> 7, n = rr & 127;
                    outU[(((long)sec * 3072 + w * 6 + h) * 128 + n) * 32 + d] = f2bf(v);
                } else {
                    int w = rr >> 7, tt = rr & 127;
                    int bb2 = w >> 8, rem = w & 255;
                    int dw = rem >> 6, hw = (rem >> 3) & 7, ww = rem & 7;
                    int td = tt >> 6, th = (tt >> 3) & 7, tw = tt & 7;
                    int d = (dw * 2 + td + 1) & 7;
                    int hh = (hw * 8 + th + 4) & 63;
                    int wo = (ww * 8 + tw + 4) & 63;
                    long src = ((long)((bb2 * 8 + d) * 64 + hh) * 64 + wo) * 192 + col;
                    outU[src] = f2bf(addsrc[src] + v + bias[col]);   // x1 in bf16
                }
            }
        }
    }
}

// ---------------- fused LN2 + MLP1 + GELU + MLP2 + residual (x1 in bf16) ----------------
// One block = 64 token rows, 512 threads (8 waves). LDS in MFMA-FRAGMENT-PACKED layout.
// 3 phases of 256 hidden cols each (2 chunks/phase): GEMM1 (2 nf frags/wave, 48 MFMA)
// -> gelu -> H_s (32 frags) -> barrier -> GEMM2 (K=256, 48 MFMA) -> barrier.
// 7 barriers/block vs 13 in the 1-chunk version.
__global__ __launch_bounds__(512, 4) void k_mlp(const unsigned short* __restrict__ x1,
                                                const float* __restrict__ g2, const float* __restrict__ b2,
                                                const unsigned short* __restrict__ wf1pk,
                                                const unsigned short* __restrict__ wf2pk,
                                                const float* __restrict__ bf1v, const float* __restrict__ bf2v,
                                                float* __restrict__ out) {
    __shared__ __align__(16) unsigned short A_s[24 * 512];  // 24576 B
    __shared__ __align__(16) unsigned short H_s[32 * 512];  // 32768 B  (total 56KB -> 2 blocks/CU)
    int tid = threadIdx.x;
    int wid = tid >> 6, lane = tid & 63;
    int g = lane >> 4, li = lane & 15;
    long r0 = (long)blockIdx.x * 64;

    // ---- LN2 stage: 8 threads per row, 24 bf16 each; write in packed-frag layout ----
    {
        int row = tid >> 3;
        int c0 = (tid & 7) * 24;
        const unsigned short* xp = x1 + (r0 + row) * 192 + c0;
        float v[24];
        #pragma unroll
        for (int q = 0; q < 3; q++) {
            ush8 f = *(const ush8*)(xp + q * 8);
            #pragma unroll
            for (int e = 0; e < 8; e++) v[q * 8 + e] = bf2f(f[e]);
        }
        float s = 0.f, ss = 0.f;
        #pragma unroll
        for (int q = 0; q < 24; q++) { s += v[q]; ss += v[q] * v[q]; }
        #pragma unroll
        for (int m = 1; m < 8; m <<= 1) { s += __shfl_xor(s, m); ss += __shfl_xor(ss, m); }
        float mu = s * (1.f / 192.f);
        float var = ss * (1.f / 192.f) - mu * mu;
        float inv = rsqrtf(var + 1e-5f);
        ush8 o[3];
        #pragma unroll
        for (int q = 0; q < 24; q++) {
            float gv = g2[c0 + q], bv = b2[c0 + q];
            o[q >> 3][q & 7] = f2bf((v[q] - mu) * inv * gv + bv);
        }
        #pragma unroll
        for (int q = 0; q < 3; q++) {
            int cb = c0 + q * 8;
            int fi = (row >> 4) * 6 + (cb >> 5);            // frag index (mf*6+kf)
            int l2 = (((cb >> 3) & 3) << 4) | (row & 15);   // dest lane in frag
            *(ush8*)&A_s[(fi * 64 + l2) * 8] = o[q];
        }
    }
    __syncthreads();

    int mw = wid >> 2, nw = wid & 3;            // GEMM2 roles: token half, out-col quarter
    int kbase = (wid >> 1) & 3;                  // hidden-32 sub-index within a 128-chunk
    int gpos = ((wid & 1) << 1) | (li >> 3);     // position-in-frag for H writes
    int e = li & 7;
    f32x4 acc2[2][3];
    #pragma unroll
    for (int i = 0; i < 2; i++)
        #pragma unroll
        for (int j = 0; j < 3; j++) acc2[i][j] = (f32x4){0.f, 0.f, 0.f, 0.f};

    for (int p = 0; p < 3; p++) {
        // GEMM1: wave owns nf0 = (2p)*8+wid and nf1 = (2p+1)*8+wid (2x16 hidden cols), all 64 tokens
        f32x4 acc1a[4], acc1b[4];
        #pragma unroll
        for (int i = 0; i < 4; i++) { acc1a[i] = (f32x4){0.f,0.f,0.f,0.f}; acc1b[i] = (f32x4){0.f,0.f,0.f,0.f}; }
        int nf0 = (p * 2) * 8 + wid, nf1 = (p * 2 + 1) * 8 + wid;
        float bv1a = bf1v[nf0 * 16 + li];
        float bv1b = bf1v[nf1 * 16 + li];
        #pragma unroll
        for (int kf = 0; kf < 6; kf++) {
            bf16x8 b0 = *(const bf16x8*)&wf1pk[(((long)nf0 * 6 + kf) * 64 + lane) * 8];
            bf16x8 b1 = *(const bf16x8*)&wf1pk[(((long)nf1 * 6 + kf) * 64 + lane) * 8];
            __builtin_amdgcn_s_setprio(1);
            #pragma unroll
            for (int mf = 0; mf < 4; mf++) {
                bf16x8 a = *(const bf16x8*)&A_s[(((mf * 6 + kf) * 64) + lane) * 8];
                acc1a[mf] = __builtin_amdgcn_mfma_f32_16x16x32_bf16(a, b0, acc1a[mf], 0, 0, 0);
                acc1b[mf] = __builtin_amdgcn_mfma_f32_16x16x32_bf16(a, b1, acc1b[mf], 0, 0, 0);
            }
            __builtin_amdgcn_s_setprio(0);
        }
        // bias + gelu + write both H chunks in packed-frag layout
        // chunk c: kfrag = c*4 + kbase; lane l2 = gpos*16 + (g*4+r); elem e = li&7
        #pragma unroll
        for (int mf = 0; mf < 4; mf++)
            #pragma unroll
            for (int r = 0; r < 4; r++) {
                int l2 = (gpos << 4) | (g * 4 + r);
                H_s[((mf * 8 + 0 * 4 + kbase) * 64 + l2) * 8 + e] = f2bf(fast_gelu(acc1a[mf][r] + bv1a));
                H_s[((mf * 8 + 1 * 4 + kbase) * 64 + l2) * 8 + e] = f2bf(fast_gelu(acc1b[mf][r] + bv1b));
            }
        __syncthreads();
        // GEMM2 partial: out[mw*32.., nw*48..] += H_phase @ Wf2[:, phase-cols]^T (K=256)
        #pragma unroll
        for (int kf = 0; kf < 8; kf++) {
            bf16x8 hf[2], bf[3];
            #pragma unroll
            for (int mf = 0; mf < 2; mf++)
                hf[mf] = *(const bf16x8*)&H_s[(((mw * 2 + mf) * 8 + kf) * 64 + lane) * 8];
            #pragma unroll
            for (int jf = 0; jf < 3; jf++)
                bf[jf] = *(const bf16x8*)&wf2pk[(((long)(nw * 3 + jf) * 24 + p * 8 + kf) * 64 + lane) * 8];
            __builtin_amdgcn_s_setprio(1);
            #pragma unroll
            for (int mf = 0; mf < 2; mf++)
                #pragma unroll
                for (int jf = 0; jf < 3; jf++)
                    acc2[mf][jf] = __builtin_amdgcn_mfma_f32_16x16x32_bf16(hf[mf], bf[jf], acc2[mf][jf], 0, 0, 0);
            __builtin_amdgcn_s_setprio(0);
        }
        __syncthreads();
    }

    // epilogue: out = x1 + acc2 + bf2
    #pragma unroll
    for (int mf = 0; mf < 2; mf++) {
        #pragma unroll
        for (int jf = 0; jf < 3; jf++) {
            int col = nw * 48 + jf * 16 + li;
            float bv = bf2v[col];
            #pragma unroll
            for (int r = 0; r < 4; r++) {
                int row = mw * 32 + mf * 16 + g * 4 + r;
                long idx = (r0 + row) * 192 + col;
                out[idx] = bf2f(x1[idx]) + acc2[mf][jf][r] + bv;
            }
        }
    }
}

// ---------------- attention: one block per (window, head) ----------------
__global__ __launch_bounds__(256, 3) void k_attn(const unsigned short* __restrict__ qkv,
                                                 const float* __restrict__ bmt,
                                                 unsigned short* __restrict__ attnout) {
    __shared__ __align__(16) char smem[42496];
    unsigned short* q_s  = (unsigned short*)smem;
    unsigned short* k_s  = q_s + 128 * 36;
    unsigned short* p_s  = (unsigned short*)smem;
    unsigned short* vt_s = (unsigned short*)(smem + 33792);

    int w = blockIdx.x, h = blockIdx.y;
    int tid = threadIdx.x, wid = tid >> 6, lane = tid & 63, g = lane >> 4, li = lane & 15;
    int rem = w & 255;
    int dw = rem >> 6, hw = (rem >> 3) & 7, ww = rem & 7;
    int variant = (dw == 3 ? 1 : 0) | (hw == 7 ? 2 : 0) | (ww == 7 ? 4 : 0);
    const float* bm = bmt + (long)(h * 8 + variant) * 16384;

    const unsigned short* qg = qkv + (long)(w * 6 + h) * 4096;
    const unsigned short* kg = qg + (long)3072 * 4096;
    const unsigned short* vg = qg + (long)6144 * 4096;

    #pragma unroll
    for (int c = tid; c < 512; c += 256) {
        int row = c >> 2, sub = c & 3;
        *(uint4*)&q_s[row * 36 + sub * 8] = *(const uint4*)&qg[row * 32 + sub * 8];
        *(uint4*)&k_s[row * 36 + sub * 8] = *(const uint4*)&kg[row * 32 + sub * 8];
    }
    {
        int key = tid >> 1, d0 = (tid & 1) * 16;
        const unsigned short* vp = vg + key * 32 + d0;
        ush8 va = *(const ush8*)vp, vb = *(const ush8*)(vp + 8);
        #pragma unroll
        for (int dd = 0; dd < 8; dd++) vt_s[(d0 + dd) * 136 + key] = va[dd];
        #pragma unroll
        for (int dd = 0; dd < 8; dd++) vt_s[(d0 + 8 + dd) * 136 + key] = vb[dd];
    }
    __syncthreads();

    f32x4 s[2][8];
    #pragma unroll
    for (int i = 0; i < 2; i++)
        #pragma unroll
        for (int j = 0; j < 8; j++) s[i][j] = (f32x4){0.f, 0.f, 0.f, 0.f};
    bf16x8 qa[2];
    #pragma unroll
    for (int fm = 0; fm < 2; fm++)
        qa[fm] = *(const bf16x8*)&q_s[(wid * 32 + fm * 16 + li) * 36 + g * 8];
    __builtin_amdgcn_s_setprio(1);
    #pragma unroll
    for (int fn = 0; fn < 8; fn++) {
        bf16x8 kb = *(const bf16x8*)&k_s[(fn * 16 + li) * 36 + g * 8];
        s[0][fn] = __builtin_amdgcn_mfma_f32_16x16x32_bf16(qa[0], kb, s[0][fn], 0, 0, 0);
        s[1][fn] = __builtin_amdgcn_mfma_f32_16x16x32_bf16(qa[1], kb, s[1][fn], 0, 0, 0);
    }
    __builtin_amdgcn_s_setprio(0);
    __syncthreads();

    #pragma unroll
    for (int fm = 0; fm < 2; fm++) {
        #pragma unroll
        for (int r = 0; r < 4; r++) {
            int i = wid * 32 + fm * 16 + g * 4 + r;
            const float4 b0 = *(const float4*)&bm[i * 128 + li * 8];
            const float4 b1 = *(const float4*)&bm[i * 128 + li * 8 + 4];
            float vals[8];
            vals[0] = s[fm][0][r] + b0.x; vals[1] = s[fm][1][r] + b0.y;
            vals[2] = s[fm][2][r] + b0.z; vals[3] = s[fm][3][r] + b0.w;
            vals[4] = s[fm][4][r] + b1.x; vals[5] = s[fm][5][r] + b1.y;
            vals[6] = s[fm][6][r] + b1.z; vals[7] = s[fm][7][r] + b1.w;
            float mx = fmaxf(fmaxf(fmaxf(vals[0], vals[1]), fmaxf(vals[2], vals[3])),
                             fmaxf(fmaxf(vals[4], vals[5]), fmaxf(vals[6], vals[7])));
            #pragma unroll
            for (int m = 1; m < 16; m <<= 1) mx = fmaxf(mx, __shfl_xor(mx, m, 16));
            float sum = 0.f;
            #pragma unroll
            for (int fn = 0; fn < 8; fn++) { vals[fn] = __expf(vals[fn] - mx); sum += vals[fn]; }
            #pragma unroll
            for (int m = 1; m < 16; m <<= 1) sum += __shfl_xor(sum, m, 16);
            float inv = __builtin_amdgcn_rcpf(sum);
            #pragma unroll
            for (int fn = 0; fn < 8; fn++)
                p_s[i * 132 + fn * 16 + li] = f2bf(vals[fn] * inv);
        }
    }

    f32x4 o[2][2];
    #pragma unroll
    for (int i = 0; i < 2; i++)
        #pragma unroll
        for (int j = 0; j < 2; j++) o[i][j] = (f32x4){0.f, 0.f, 0.f, 0.f};
    __builtin_amdgcn_s_setprio(1);
    #pragma unroll
    for (int ks = 0; ks < 4; ks++) {
        bf16x8 pa[2];
        #pragma unroll
        for (int fm = 0; fm < 2; fm++)
            pa[fm] = *(const bf16x8*)&p_s[(wid * 32 + fm * 16 + li) * 132 + ks * 32 + g * 8];
        #pragma unroll
        for (int fn = 0; fn < 2; fn++) {
            bf16x8 vb = *(const bf16x8*)&vt_s[(fn * 16 + li) * 136 + ks * 32 + g * 8];
            o[0][fn] = __builtin_amdgcn_mfma_f32_16x16x32_bf16(pa[0], vb, o[0][fn], 0, 0, 0);
            o[1][fn] = __builtin_amdgcn_mfma_f32_16x16x32_bf16(pa[1], vb, o[1][fn], 0, 0, 0);
        }
    }
    __builtin_amdgcn_s_setprio(0);

    unsigned short* op = attnout + (long)w * 128 * 192 + h * 32;
    #pragma unroll
    for (int fm = 0; fm < 2; fm++) {
        #pragma unroll
        for (int fn = 0; fn < 2; fn++) {
            #pragma unroll
            for (int r = 0; r < 4; r++) {
                int n = wid * 32 + fm * 16 + g * 4 + r;
                op[(long)n * 192 + fn * 16 + li] = f2bf(o[fm][fn][r]);
            }
        }
    }
}

// ---------------- host ----------------
extern "C" void kernel_launch(void* const* d_in, const int* in_sizes, int n_in,
                              void* d_out, int out_size, void* d_ws, size_t ws_size,
                              hipStream_t stream) {
    const float* x   = (const float*)d_in[0];
    const float* g1  = (const float*)d_in[1];
    const float* b1  = (const float*)d_in[2];
    const float* Wq  = (const float*)d_in[3];
    const float* Wkv = (const float*)d_in[4];
    const float* rpb = (const float*)d_in[5];
    const float* Wp  = (const float*)d_in[6];
    const float* bp  = (const float*)d_in[7];
    const float* g2  = (const float*)d_in[8];
    const float* b2  = (const float*)d_in[9];
    const float* Wf1 = (const float*)d_in[10];
    const float* bf1 = (const float*)d_in[11];
    const float* Wf2 = (const float*)d_in[12];
    const float* bf2 = (const float*)d_in[13];
    float* out = (float*)d_out;
    char* ws = (char*)d_ws;

    unsigned short* wpk  = (unsigned short*)ws;               // 884736 B
    float* bmt           = (float*)(ws + 917504);             // 3145728 B -> ends 4063232
    unsigned short* xw   = (unsigned short*)(ws + 4194304);   // 25165824 B -> ends 29360128
    unsigned short* qkvb = (unsigned short*)(ws + 29360128);  // 75497472 B -> ends 104857600
    unsigned short* attb = xw;                                // reuse after QKV consumed
    unsigned short* x1b  = (unsigned short*)(ws + 29360128);  // 25165824 B bf16 (reuses qkv region)

    const unsigned short* qkvpk = wpk;
    const unsigned short* wppk  = wpk + 110592;
    const unsigned short* wf1pk = wpk + 147456;
    const unsigned short* wf2pk = wpk + 294912;

    k_pack<<<216, 256, 0, stream>>>(Wq, Wkv, Wp, Wf1, Wf2, wpk);
    k_bmt<<<3072, 256, 0, stream>>>(rpb, bmt);
    k_ln<<<16384, 256, 0, stream>>>(x, g1, b1, xw);
    k_gemm<0><<<dim3(9, 256), 256, 0, stream>>>(xw, qkvpk, 192, nullptr, nullptr, qkvb);
    k_attn<<<dim3(512, 6), 256, 0, stream>>>(qkvb, bmt, attb);
    k_gemm<1><<<dim3(3, 256), 256, 0, stream>>>(attb, wppk, 192, bp, x, x1b);
    k_mlp<<<1024, 512, 0, stream>>>(x1b, g2, b2, wf1pk, wf2pk, bf1, bf2, out);
}

// Round 16
// 214.835 us; speedup vs baseline: 1.0403x; 1.0403x over previous
//
#include <hip/hip_runtime.h>
#include <cstdint>

#define DEVI static __device__ __forceinline__

typedef __attribute__((ext_vector_type(8))) short bf16x8;
typedef __attribute__((ext_vector_type(4))) float f32x4;
typedef __attribute__((ext_vector_type(8))) unsigned short ush8;

DEVI unsigned short f2bf(float f) {
    unsigned u = __float_as_uint(f);
    u += 0x7fff + ((u >> 16) & 1);
    return (unsigned short)(u >> 16);
}
DEVI float bf2f(unsigned short h) { return __uint_as_float(((unsigned)h) << 16); }

DEVI void gload16(const void* g, void* l) {
    __builtin_amdgcn_global_load_lds((const __attribute__((address_space(1))) void*)g,
                                     (__attribute__((address_space(3))) void*)l, 16, 0, 0);
}

DEVI float fast_gelu(float x) {
    // tanh-approx GELU via raw v_rcp_f32 (no -ffast-math; '/' would expand to ~12-op exact div)
    float z = 1.5957691216057308f * (x + 0.044715f * x * x * x);
    return x - x * __builtin_amdgcn_rcpf(__expf(z) + 1.f);
}

// ---------------- weight pack: fp32 -> bf16 in MFMA-fragment order ----------------
__global__ __launch_bounds__(256) void k_pack(const float* __restrict__ Wq, const float* __restrict__ Wkv,
                                              const float* __restrict__ Wp, const float* __restrict__ Wf1,
                                              const float* __restrict__ Wf2, unsigned short* __restrict__ dst) {
    int t = blockIdx.x * 256 + threadIdx.x;
    if (t >= 55296) return;
    int c, base, K;
    const float* src = nullptr;
    if (t < 13824)      { c = t;         base = 0;      K = 192; }
    else if (t < 18432) { c = t - 13824; base = 110592; K = 192; src = Wp; }
    else if (t < 36864) { c = t - 18432; base = 147456; K = 192; src = Wf1; }
    else                { c = t - 36864; base = 294912; K = 768; src = Wf2; }
    int lane = c & 63, fk = c >> 6, Kf = K >> 5;
    int kf = fk % Kf, nf = fk / Kf;
    int row = nf * 16 + (lane & 15), col = kf * 32 + (lane >> 4) * 8;
    ush8 o;
    if (t < 13824) {
        if (row < 192) {
            #pragma unroll
            for (int q = 0; q < 8; q++) o[q] = f2bf(Wq[row * 192 + col + q] * 0.17677669529663687f);
        } else {
            #pragma unroll
            for (int q = 0; q < 8; q++) o[q] = f2bf(Wkv[(row - 192) * 192 + col + q]);
        }
    } else {
        #pragma unroll
        for (int q = 0; q < 8; q++) o[q] = f2bf(src[(long)row * K + col + q]);
    }
    *(ush8*)&dst[base + c * 8] = o;
}

// ---------------- fused bias+mask table: [6 heads][8 variants][128 i][16 li][8 fn] f32 ----------------
__global__ __launch_bounds__(256) void k_bmt(const float* __restrict__ rpb, float* __restrict__ bmt) {
    int t = blockIdx.x * 256 + threadIdx.x;  // 6 * 131072
    int h = t >> 17;
    int r = t & 131071;
    int v = r >> 14;
    int ij = r & 16383;
    int i = ij >> 7, li = (ij >> 3) & 15, fn = ij & 7;
    int j = fn * 16 + li;
    int tdi = i >> 6, thi = (i >> 3) & 7, twi = i & 7;
    int tdj = j >> 6, thj = (j >> 3) & 7, twj = j & 7;
    int idx = ((tdi - tdj + 1) * 15 + (thi - thj + 7)) * 15 + (twi - twj + 7);
    float b = rpb[idx * 6 + h];
    int dwb = v & 1, hwb = (v >> 1) & 1, wwb = (v >> 2) & 1;
    int ri = (dwb ? 1 + tdi : 0) * 9 + (hwb ? (thi < 4 ? 1 : 2) : 0) * 3 + (wwb ? (twi < 4 ? 1 : 2) : 0);
    int rj = (dwb ? 1 + tdj : 0) * 9 + (hwb ? (thj < 4 ? 1 : 2) : 0) * 3 + (wwb ? (twj < 4 ? 1 : 2) : 0);
    if (ri != rj) b -= 100.f;
    bmt[(long)(h * 8 + v) * 16384 + i * 128 + li * 8 + fn] = b;
}

// ---------------- LayerNorm fused with roll+window gather ----------------
__global__ __launch_bounds__(256) void k_ln(const float* __restrict__ x, const float* __restrict__ g,
                                            const float* __restrict__ b, unsigned short* __restrict__ outp) {
    int wid = threadIdx.x >> 6, lane = threadIdx.x & 63;
    int t = blockIdx.x * 4 + wid;
    int w = t >> 7, tt = t & 127;
    int bb = w >> 8, rem = w & 255;
    int dw = rem >> 6, hw = (rem >> 3) & 7, ww = rem & 7;
    int td = tt >> 6, th = (tt >> 3) & 7, tw = tt & 7;
    int d = (dw * 2 + td + 1) & 7;
    int hh = (hw * 8 + th + 4) & 63;
    int wo = (ww * 8 + tw + 4) & 63;
    long src = (long)((bb * 8 + d) * 64 + hh) * 64 + wo;
    const float* xp = x + src * 192;
    float v0 = xp[lane], v1 = xp[lane + 64], v2 = xp[lane + 128];
    float s = v0 + v1 + v2, ss = v0 * v0 + v1 * v1 + v2 * v2;
    #pragma unroll
    for (int m = 32; m; m >>= 1) { s += __shfl_xor(s, m); ss += __shfl_xor(ss, m); }
    float mu = s * (1.f / 192.f);
    float var = ss * (1.f / 192.f) - mu * mu;
    float inv = rsqrtf(var + 1e-5f);
    unsigned short* op = outp + (long)t * 192;
    op[lane]       = f2bf((v0 - mu) * inv * g[lane]       + b[lane]);
    op[lane + 64]  = f2bf((v1 - mu) * inv * g[lane + 64]  + b[lane + 64]);
    op[lane + 128] = f2bf((v2 - mu) * inv * g[lane + 128] + b[lane + 128]);
}

// ---------------- bf16 MFMA GEMM: C[M,N] = A[M,K] @ B[N,K]^T, B in packed-frag form ----------------
// EPI: 0=QKV scatter (bf16 out), 1=proj + window-reverse + residual -> x1 bf16
template <int EPI>
__global__ __launch_bounds__(256, 4) void k_gemm(const unsigned short* __restrict__ A,
                                                 const unsigned short* __restrict__ Bpk, int K,
                                                 const float* __restrict__ bias,
                                                 const float* __restrict__ addsrc,
                                                 unsigned short* __restrict__ outU) {
    __shared__ __align__(16) unsigned short As[2][256 * 32];
    int tid = threadIdx.x;
    int wid = tid >> 6, lane = tid & 63;
    int g = lane >> 4, li = lane & 15;
    int m0 = blockIdx.y * 256, n0 = blockIdx.x * 64;
    int Kf = K >> 5;

    f32x4 acc[4][4];
    #pragma unroll
    for (int i = 0; i < 4; i++)
        #pragma unroll
        for (int j = 0; j < 4; j++) acc[i][j] = (f32x4){0.f, 0.f, 0.f, 0.f};

    int sg = ((tid & 3) ^ ((tid >> 3) & 3)) * 8;
    const unsigned short* pa = A + (long)(m0 + (tid >> 2)) * K + sg;
    const unsigned short* pbk = Bpk + ((long)(n0 >> 4) * Kf * 64 + lane) * 8;

#define STAGE(buf, kt) do { \
    _Pragma("unroll") \
    for (int c = 0; c < 4; c++) \
        gload16(pa + (long)(c * 64) * K + (kt), &As[buf][c * 2048 + tid * 8]); \
} while (0)

    STAGE(0, 0);
    __syncthreads();

    int cur = 0;
    int acol = (g ^ ((li >> 1) & 3)) * 8;
    for (int t = 0; t < Kf; t++) {
        bf16x8 bfr[4];
        #pragma unroll
        for (int j = 0; j < 4; j++)
            bfr[j] = *(const bf16x8*)(pbk + ((long)j * Kf + t) * 512);
        if (t + 1 < Kf) STAGE(cur ^ 1, (t + 1) << 5);
        const unsigned short* ab = &As[cur][(wid * 64 + li) * 32 + acol];
        bf16x8 af[4];
        #pragma unroll
        for (int i = 0; i < 4; i++) af[i] = *(const bf16x8*)(ab + i * 512);
        __builtin_amdgcn_s_setprio(1);
        #pragma unroll
        for (int i = 0; i < 4; i++)
            #pragma unroll
            for (int j = 0; j < 4; j++)
                acc[i][j] = __builtin_amdgcn_mfma_f32_16x16x32_bf16(af[i], bfr[j], acc[i][j], 0, 0, 0);
        __builtin_amdgcn_s_setprio(0);
        if (t + 1 < Kf) {
            __syncthreads();
            cur ^= 1;
        }
    }
#undef STAGE

    #pragma unroll
    for (int i = 0; i < 4; i++) {
        int rowb = m0 + wid * 64 + i * 16 + g * 4;
        #pragma unroll
        for (int j = 0; j < 4; j++) {
            int col = n0 + j * 16 + li;
            #pragma unroll
            for (int r = 0; r < 4; r++) {
                float v = acc[i][j][r];
                int rr = rowb + r;
                if (EPI == 0) {
                    int sec = col / 192;
                    int cc = col - sec * 192;
                    int h = cc >> 5, d = cc & 31;
                    int w = rr >> 7, n = rr & 127;
                    outU[(((long)sec * 3072 + w * 6 + h) * 128 + n) * 32 + d] = f2bf(v);
                } else {
                    int w = rr >> 7, tt = rr & 127;
                    int bb2 = w >> 8, rem = w & 255;
                    int dw = rem >> 6, hw = (rem >> 3) & 7, ww = rem & 7;
                    int td = tt >> 6, th = (tt >> 3) & 7, tw = tt & 7;
                    int d = (dw * 2 + td + 1) & 7;
                    int hh = (hw * 8 + th + 4) & 63;
                    int wo = (ww * 8 + tw + 4) & 63;
                    long src = ((long)((bb2 * 8 + d) * 64 + hh) * 64 + wo) * 192 + col;
                    outU[src] = f2bf(addsrc[src] + v + bias[col]);   // x1 in bf16
                }
            }
        }
    }
}

// ---------------- fused LN2 + MLP1 + GELU + MLP2 + residual (x1 in bf16) ----------------
// One block = 64 token rows, 512 threads (8 waves). LDS in MFMA-FRAGMENT-PACKED layout
// (frag = 64 lanes x 16B contiguous -> conflict-free 1KB wave reads). 40KB LDS.
__global__ __launch_bounds__(512, 4) void k_mlp(const unsigned short* __restrict__ x1,
                                                const float* __restrict__ g2, const float* __restrict__ b2,
                                                const unsigned short* __restrict__ wf1pk,
                                                const unsigned short* __restrict__ wf2pk,
                                                const float* __restrict__ bf1v, const float* __restrict__ bf2v,
                                                float* __restrict__ out) {
    __shared__ __align__(16) unsigned short A_s[24 * 512];  // 24576 B
    __shared__ __align__(16) unsigned short H_s[16 * 512];  // 16384 B
    int tid = threadIdx.x;
    int wid = tid >> 6, lane = tid & 63;
    int g = lane >> 4, li = lane & 15;
    long r0 = (long)blockIdx.x * 64;

    // ---- LN2 stage: 8 threads per row, 24 bf16 each; write in packed-frag layout ----
    {
        int row = tid >> 3;
        int c0 = (tid & 7) * 24;
        const unsigned short* xp = x1 + (r0 + row) * 192 + c0;
        float v[24];
        #pragma unroll
        for (int q = 0; q < 3; q++) {
            ush8 f = *(const ush8*)(xp + q * 8);
            #pragma unroll
            for (int e = 0; e < 8; e++) v[q * 8 + e] = bf2f(f[e]);
        }
        float s = 0.f, ss = 0.f;
        #pragma unroll
        for (int q = 0; q < 24; q++) { s += v[q]; ss += v[q] * v[q]; }
        #pragma unroll
        for (int m = 1; m < 8; m <<= 1) { s += __shfl_xor(s, m); ss += __shfl_xor(ss, m); }
        float mu = s * (1.f / 192.f);
        float var = ss * (1.f / 192.f) - mu * mu;
        float inv = rsqrtf(var + 1e-5f);
        ush8 o[3];
        #pragma unroll
        for (int q = 0; q < 24; q++) {
            float gv = g2[c0 + q], bv = b2[c0 + q];
            o[q >> 3][q & 7] = f2bf((v[q] - mu) * inv * gv + bv);
        }
        #pragma unroll
        for (int q = 0; q < 3; q++) {
            int cb = c0 + q * 8;
            int fi = (row >> 4) * 6 + (cb >> 5);            // frag index (mf*6+kf)
            int l2 = (((cb >> 3) & 3) << 4) | (row & 15);   // dest lane in frag
            *(ush8*)&A_s[(fi * 64 + l2) * 8] = o[q];
        }
    }
    __syncthreads();

    int mw = wid >> 2, nw = wid & 3;            // GEMM2 roles: token half, out-col quarter
    int kf2 = wid >> 1;                          // this wave's hidden-frag in GEMM1 output
    int gpos = ((wid & 1) << 1) | (li >> 3);     // position-in-frag for H writes
    int e = li & 7;
    f32x4 acc2[2][3];
    #pragma unroll
    for (int i = 0; i < 2; i++)
        #pragma unroll
        for (int j = 0; j < 3; j++) acc2[i][j] = (f32x4){0.f, 0.f, 0.f, 0.f};

    for (int ch = 0; ch < 6; ch++) {
        // GEMM1: wave owns hidden frag nf = ch*8 + wid (16 cols), all 64 tokens
        f32x4 acc1[4];
        #pragma unroll
        for (int i = 0; i < 4; i++) acc1[i] = (f32x4){0.f, 0.f, 0.f, 0.f};
        int nf = ch * 8 + wid;
        float bv1 = bf1v[ch * 128 + wid * 16 + li];
        #pragma unroll
        for (int kf = 0; kf < 6; kf++) {
            bf16x8 b = *(const bf16x8*)&wf1pk[(((long)nf * 6 + kf) * 64 + lane) * 8];
            __builtin_amdgcn_s_setprio(1);
            #pragma unroll
            for (int mf = 0; mf < 4; mf++) {
                bf16x8 a = *(const bf16x8*)&A_s[(((mf * 6 + kf) * 64) + lane) * 8];
                acc1[mf] = __builtin_amdgcn_mfma_f32_16x16x32_bf16(a, b, acc1[mf], 0, 0, 0);
            }
            __builtin_amdgcn_s_setprio(0);
        }
        // hoist W2 loads for kf=0,1 across the barrier
        bf16x8 w2p[2][3];
        #pragma unroll
        for (int kf = 0; kf < 2; kf++)
            #pragma unroll
            for (int jf = 0; jf < 3; jf++)
                w2p[kf][jf] = *(const bf16x8*)&wf2pk[(((long)(nw * 3 + jf) * 24 + ch * 4 + kf) * 64 + lane) * 8];
        // bias + gelu + write H chunk in packed-frag layout
        #pragma unroll
        for (int mf = 0; mf < 4; mf++)
            #pragma unroll
            for (int r = 0; r < 4; r++) {
                int l2 = (gpos << 4) | (g * 4 + r);
                H_s[((mf * 4 + kf2) * 64 + l2) * 8 + e] = f2bf(fast_gelu(acc1[mf][r] + bv1));
            }
        __syncthreads();
        // GEMM2 partial: out[mw*32.., nw*48..] += H_chunk @ Wf2[:, ch-cols]^T
        #pragma unroll
        for (int kf = 0; kf < 4; kf++) {
            bf16x8 hf[2], bf[3];
            #pragma unroll
            for (int mf = 0; mf < 2; mf++)
                hf[mf] = *(const bf16x8*)&H_s[(((mw * 2 + mf) * 4 + kf) * 64 + lane) * 8];
            if (kf < 2) {
                #pragma unroll
                for (int jf = 0; jf < 3; jf++) bf[jf] = w2p[kf][jf];
            } else {
                #pragma unroll
                for (int jf = 0; jf < 3; jf++)
                    bf[jf] = *(const bf16x8*)&wf2pk[(((long)(nw * 3 + jf) * 24 + ch * 4 + kf) * 64 + lane) * 8];
            }
            __builtin_amdgcn_s_setprio(1);
            #pragma unroll
            for (int mf = 0; mf < 2; mf++)
                #pragma unroll
                for (int jf = 0; jf < 3; jf++)
                    acc2[mf][jf] = __builtin_amdgcn_mfma_f32_16x16x32_bf16(hf[mf], bf[jf], acc2[mf][jf], 0, 0, 0);
            __builtin_amdgcn_s_setprio(0);
        }
        __syncthreads();
    }

    // epilogue: out = x1 + acc2 + bf2
    #pragma unroll
    for (int mf = 0; mf < 2; mf++) {
        #pragma unroll
        for (int jf = 0; jf < 3; jf++) {
            int col = nw * 48 + jf * 16 + li;
            float bv = bf2v[col];
            #pragma unroll
            for (int r = 0; r < 4; r++) {
                int row = mw * 32 + mf * 16 + g * 4 + r;
                long idx = (r0 + row) * 192 + col;
                out[idx] = bf2f(x1[idx]) + acc2[mf][jf][r] + bv;
            }
        }
    }
}

// ---------------- attention: one block per (window, head) ----------------
__global__ __launch_bounds__(256, 3) void k_attn(const unsigned short* __restrict__ qkv,
                                                 const float* __restrict__ bmt,
                                                 unsigned short* __restrict__ attnout) {
    __shared__ __align__(16) char smem[42496];
    unsigned short* q_s  = (unsigned short*)smem;
    unsigned short* k_s  = q_s + 128 * 36;
    unsigned short* p_s  = (unsigned short*)smem;
    unsigned short* vt_s = (unsigned short*)(smem + 33792);

    int w = blockIdx.x, h = blockIdx.y;
    int tid = threadIdx.x, wid = tid >> 6, lane = tid & 63, g = lane >> 4, li = lane & 15;
    int rem = w & 255;
    int dw = rem >> 6, hw = (rem >> 3) & 7, ww = rem & 7;
    int variant = (dw == 3 ? 1 : 0) | (hw == 7 ? 2 : 0) | (ww == 7 ? 4 : 0);
    const float* bm = bmt + (long)(h * 8 + variant) * 16384;

    const unsigned short* qg = qkv + (long)(w * 6 + h) * 4096;
    const unsigned short* kg = qg + (long)3072 * 4096;
    const unsigned short* vg = qg + (long)6144 * 4096;

    #pragma unroll
    for (int c = tid; c < 512; c += 256) {
        int row = c >> 2, sub = c & 3;
        *(uint4*)&q_s[row * 36 + sub * 8] = *(const uint4*)&qg[row * 32 + sub * 8];
        *(uint4*)&k_s[row * 36 + sub * 8] = *(const uint4*)&kg[row * 32 + sub * 8];
    }
    {
        int key = tid >> 1, d0 = (tid & 1) * 16;
        const unsigned short* vp = vg + key * 32 + d0;
        ush8 va = *(const ush8*)vp, vb = *(const ush8*)(vp + 8);
        #pragma unroll
        for (int dd = 0; dd < 8; dd++) vt_s[(d0 + dd) * 136 + key] = va[dd];
        #pragma unroll
        for (int dd = 0; dd < 8; dd++) vt_s[(d0 + 8 + dd) * 136 + key] = vb[dd];
    }
    __syncthreads();

    f32x4 s[2][8];
    #pragma unroll
    for (int i = 0; i < 2; i++)
        #pragma unroll
        for (int j = 0; j < 8; j++) s[i][j] = (f32x4){0.f, 0.f, 0.f, 0.f};
    bf16x8 qa[2];
    #pragma unroll
    for (int fm = 0; fm < 2; fm++)
        qa[fm] = *(const bf16x8*)&q_s[(wid * 32 + fm * 16 + li) * 36 + g * 8];
    __builtin_amdgcn_s_setprio(1);
    #pragma unroll
    for (int fn = 0; fn < 8; fn++) {
        bf16x8 kb = *(const bf16x8*)&k_s[(fn * 16 + li) * 36 + g * 8];
        s[0][fn] = __builtin_amdgcn_mfma_f32_16x16x32_bf16(qa[0], kb, s[0][fn], 0, 0, 0);
        s[1][fn] = __builtin_amdgcn_mfma_f32_16x16x32_bf16(qa[1], kb, s[1][fn], 0, 0, 0);
    }
    __builtin_amdgcn_s_setprio(0);
    __syncthreads();

    #pragma unroll
    for (int fm = 0; fm < 2; fm++) {
        #pragma unroll
        for (int r = 0; r < 4; r++) {
            int i = wid * 32 + fm * 16 + g * 4 + r;
            const float4 b0 = *(const float4*)&bm[i * 128 + li * 8];
            const float4 b1 = *(const float4*)&bm[i * 128 + li * 8 + 4];
            float vals[8];
            vals[0] = s[fm][0][r] + b0.x; vals[1] = s[fm][1][r] + b0.y;
            vals[2] = s[fm][2][r] + b0.z; vals[3] = s[fm][3][r] + b0.w;
            vals[4] = s[fm][4][r] + b1.x; vals[5] = s[fm][5][r] + b1.y;
            vals[6] = s[fm][6][r] + b1.z; vals[7] = s[fm][7][r] + b1.w;
            float mx = fmaxf(fmaxf(fmaxf(vals[0], vals[1]), fmaxf(vals[2], vals[3])),
                             fmaxf(fmaxf(vals[4], vals[5]), fmaxf(vals[6], vals[7])));
            #pragma unroll
            for (int m = 1; m < 16; m <<= 1) mx = fmaxf(mx, __shfl_xor(mx, m, 16));
            float sum = 0.f;
            #pragma unroll
            for (int fn = 0; fn < 8; fn++) { vals[fn] = __expf(vals[fn] - mx); sum += vals[fn]; }
            #pragma unroll
            for (int m = 1; m < 16; m <<= 1) sum += __shfl_xor(sum, m, 16);
            float inv = __builtin_amdgcn_rcpf(sum);
            #pragma unroll
            for (int fn = 0; fn < 8; fn++)
                p_s[i * 132 + fn * 16 + li] = f2bf(vals[fn] * inv);
        }
    }

    f32x4 o[2][2];
    #pragma unroll
    for (int i = 0; i < 2; i++)
        #pragma unroll
        for (int j = 0; j < 2; j++) o[i][j] = (f32x4){0.f, 0.f, 0.f, 0.f};
    __builtin_amdgcn_s_setprio(1);
    #pragma unroll
    for (int ks = 0; ks < 4; ks++) {
        bf16x8 pa[2];
        #pragma unroll
        for (int fm = 0; fm < 2; fm++)
            pa[fm] = *(const bf16x8*)&p_s[(wid * 32 + fm * 16 + li) * 132 + ks * 32 + g * 8];
        #pragma unroll
        for (int fn = 0; fn < 2; fn++) {
            bf16x8 vb = *(const bf16x8*)&vt_s[(fn * 16 + li) * 136 + ks * 32 + g * 8];
            o[0][fn] = __builtin_amdgcn_mfma_f32_16x16x32_bf16(pa[0], vb, o[0][fn], 0, 0, 0);
            o[1][fn] = __builtin_amdgcn_mfma_f32_16x16x32_bf16(pa[1], vb, o[1][fn], 0, 0, 0);
        }
    }
    __builtin_amdgcn_s_setprio(0);

    unsigned short* op = attnout + (long)w * 128 * 192 + h * 32;
    #pragma unroll
    for (int fm = 0; fm < 2; fm++) {
        #pragma unroll
        for (int fn = 0; fn < 2; fn++) {
            #pragma unroll
            for (int r = 0; r < 4; r++) {
                int n = wid * 32 + fm * 16 + g * 4 + r;
                op[(long)n * 192 + fn * 16 + li] = f2bf(o[fm][fn][r]);
            }
        }
    }
}

// ---------------- host ----------------
extern "C" void kernel_launch(void* const* d_in, const int* in_sizes, int n_in,
                              void* d_out, int out_size, void* d_ws, size_t ws_size,
                              hipStream_t stream) {
    const float* x   = (const float*)d_in[0];
    const float* g1  = (const float*)d_in[1];
    const float* b1  = (const float*)d_in[2];
    const float* Wq  = (const float*)d_in[3];
    const float* Wkv = (const float*)d_in[4];
    const float* rpb = (const float*)d_in[5];
    const float* Wp  = (const float*)d_in[6];
    const float* bp  = (const float*)d_in[7];
    const float* g2  = (const float*)d_in[8];
    const float* b2  = (const float*)d_in[9];
    const float* Wf1 = (const float*)d_in[10];
    const float* bf1 = (const float*)d_in[11];
    const float* Wf2 = (const float*)d_in[12];
    const float* bf2 = (const float*)d_in[13];
    float* out = (float*)d_out;
    char* ws = (char*)d_ws;

    unsigned short* wpk  = (unsigned short*)ws;               // 884736 B
    float* bmt           = (float*)(ws + 917504);             // 3145728 B -> ends 4063232
    unsigned short* xw   = (unsigned short*)(ws + 4194304);   // 25165824 B -> ends 29360128
    unsigned short* qkvb = (unsigned short*)(ws + 29360128);  // 75497472 B -> ends 104857600
    unsigned short* attb = xw;                                // reuse after QKV consumed
    unsigned short* x1b  = (unsigned short*)(ws + 29360128);  // 25165824 B bf16 (reuses qkv region)

    const unsigned short* qkvpk = wpk;
    const unsigned short* wppk  = wpk + 110592;
    const unsigned short* wf1pk = wpk + 147456;
    const unsigned short* wf2pk = wpk + 294912;

    k_pack<<<216, 256, 0, stream>>>(Wq, Wkv, Wp, Wf1, Wf2, wpk);
    k_bmt<<<3072, 256, 0, stream>>>(rpb, bmt);
    k_ln<<<16384, 256, 0, stream>>>(x, g1, b1, xw);
    k_gemm<0><<<dim3(9, 256), 256, 0, stream>>>(xw, qkvpk, 192, nullptr, nullptr, qkvb);
    k_attn<<<dim3(512, 6), 256, 0, stream>>>(qkvb, bmt, attb);
    k_gemm<1><<<dim3(3, 256), 256, 0, stream>>>(attb, wppk, 192, bp, x, x1b);
    k_mlp<<<1024, 512, 0, stream>>>(x1b, g2, b2, wf1pk, wf2pk, bf1, bf2, out);
}

// Round 17
// 214.035 us; speedup vs baseline: 1.0442x; 1.0037x over previous
//
#include <hip/hip_runtime.h>
#include <cstdint>

#define DEVI static __device__ __forceinline__

typedef __attribute__((ext_vector_type(8))) short bf16x8;
typedef __attribute__((ext_vector_type(4))) float f32x4;
typedef __attribute__((ext_vector_type(8))) unsigned short ush8;

DEVI unsigned short f2bf(float f) {
    unsigned u = __float_as_uint(f);
    u += 0x7fff + ((u >> 16) & 1);
    return (unsigned short)(u >> 16);
}
DEVI float bf2f(unsigned short h) { return __uint_as_float(((unsigned)h) << 16); }

DEVI void gload16(const void* g, void* l) {
    __builtin_amdgcn_global_load_lds((const __attribute__((address_space(1))) void*)g,
                                     (__attribute__((address_space(3))) void*)l, 16, 0, 0);
}

DEVI float fast_gelu(float x) {
    // tanh-approx GELU via raw v_rcp_f32 (no -ffast-math; '/' would expand to ~12-op exact div)
    float z = 1.5957691216057308f * (x + 0.044715f * x * x * x);
    return x - x * __builtin_amdgcn_rcpf(__expf(z) + 1.f);
}

// ---------------- weight pack: fp32 -> bf16 in MFMA-fragment order ----------------
__global__ __launch_bounds__(256) void k_pack(const float* __restrict__ Wq, const float* __restrict__ Wkv,
                                              const float* __restrict__ Wp, const float* __restrict__ Wf1,
                                              const float* __restrict__ Wf2, unsigned short* __restrict__ dst) {
    int t = blockIdx.x * 256 + threadIdx.x;
    if (t >= 55296) return;
    int c, base, K;
    const float* src = nullptr;
    if (t < 13824)      { c = t;         base = 0;      K = 192; }
    else if (t < 18432) { c = t - 13824; base = 110592; K = 192; src = Wp; }
    else if (t < 36864) { c = t - 18432; base = 147456; K = 192; src = Wf1; }
    else                { c = t - 36864; base = 294912; K = 768; src = Wf2; }
    int lane = c & 63, fk = c >> 6, Kf = K >> 5;
    int kf = fk % Kf, nf = fk / Kf;
    int row = nf * 16 + (lane & 15), col = kf * 32 + (lane >> 4) * 8;
    ush8 o;
    if (t < 13824) {
        if (row < 192) {
            #pragma unroll
            for (int q = 0; q < 8; q++) o[q] = f2bf(Wq[row * 192 + col + q] * 0.17677669529663687f);
        } else {
            #pragma unroll
            for (int q = 0; q < 8; q++) o[q] = f2bf(Wkv[(row - 192) * 192 + col + q]);
        }
    } else {
        #pragma unroll
        for (int q = 0; q < 8; q++) o[q] = f2bf(src[(long)row * K + col + q]);
    }
    *(ush8*)&dst[base + c * 8] = o;
}

// ---------------- fused bias+mask table: [6 heads][8 variants][128 i][16 li][8 fn] f32 ----------------
__global__ __launch_bounds__(256) void k_bmt(const float* __restrict__ rpb, float* __restrict__ bmt) {
    int t = blockIdx.x * 256 + threadIdx.x;  // 6 * 131072
    int h = t >> 17;
    int r = t & 131071;
    int v = r >> 14;
    int ij = r & 16383;
    int i = ij >> 7, li = (ij >> 3) & 15, fn = ij & 7;
    int j = fn * 16 + li;
    int tdi = i >> 6, thi = (i >> 3) & 7, twi = i & 7;
    int tdj = j >> 6, thj = (j >> 3) & 7, twj = j & 7;
    int idx = ((tdi - tdj + 1) * 15 + (thi - thj + 7)) * 15 + (twi - twj + 7);
    float b = rpb[idx * 6 + h];
    int dwb = v & 1, hwb = (v >> 1) & 1, wwb = (v >> 2) & 1;
    int ri = (dwb ? 1 + tdi : 0) * 9 + (hwb ? (thi < 4 ? 1 : 2) : 0) * 3 + (wwb ? (twi < 4 ? 1 : 2) : 0);
    int rj = (dwb ? 1 + tdj : 0) * 9 + (hwb ? (thj < 4 ? 1 : 2) : 0) * 3 + (wwb ? (twj < 4 ? 1 : 2) : 0);
    if (ri != rj) b -= 100.f;
    bmt[(long)(h * 8 + v) * 16384 + i * 128 + li * 8 + fn] = b;
}

// ---------------- LayerNorm fused with roll+window gather ----------------
__global__ __launch_bounds__(256) void k_ln(const float* __restrict__ x, const float* __restrict__ g,
                                            const float* __restrict__ b, unsigned short* __restrict__ outp) {
    int wid = threadIdx.x >> 6, lane = threadIdx.x & 63;
    int t = blockIdx.x * 4 + wid;
    int w = t >> 7, tt = t & 127;
    int bb = w >> 8, rem = w & 255;
    int dw = rem >> 6, hw = (rem >> 3) & 7, ww = rem & 7;
    int td = tt >> 6, th = (tt >> 3) & 7, tw = tt & 7;
    int d = (dw * 2 + td + 1) & 7;
    int hh = (hw * 8 + th + 4) & 63;
    int wo = (ww * 8 + tw + 4) & 63;
    long src = (long)((bb * 8 + d) * 64 + hh) * 64 + wo;
    const float* xp = x + src * 192;
    float v0 = xp[lane], v1 = xp[lane + 64], v2 = xp[lane + 128];
    float s = v0 + v1 + v2, ss = v0 * v0 + v1 * v1 + v2 * v2;
    #pragma unroll
    for (int m = 32; m; m >>= 1) { s += __shfl_xor(s, m); ss += __shfl_xor(ss, m); }
    float mu = s * (1.f / 192.f);
    float var = ss * (1.f / 192.f) - mu * mu;
    float inv = rsqrtf(var + 1e-5f);
    unsigned short* op = outp + (long)t * 192;
    op[lane]       = f2bf((v0 - mu) * inv * g[lane]       + b[lane]);
    op[lane + 64]  = f2bf((v1 - mu) * inv * g[lane + 64]  + b[lane + 64]);
    op[lane + 128] = f2bf((v2 - mu) * inv * g[lane + 128] + b[lane + 128]);
}

// ---------------- bf16 MFMA GEMM: C[M,N] = A[M,K] @ B[N,K]^T, B in packed-frag form ----------------
// EPI: 0=QKV scatter (bf16 out), 1=proj + window-reverse + residual -> x1 bf16
template <int EPI>
__global__ __launch_bounds__(256, 4) void k_gemm(const unsigned short* __restrict__ A,
                                                 const unsigned short* __restrict__ Bpk, int K,
                                                 const float* __restrict__ bias,
                                                 const float* __restrict__ addsrc,
                                                 unsigned short* __restrict__ outU) {
    __shared__ __align__(16) unsigned short As[2][256 * 32];
    int tid = threadIdx.x;
    int wid = tid >> 6, lane = tid & 63;
    int g = lane >> 4, li = lane & 15;
    int m0 = blockIdx.y * 256, n0 = blockIdx.x * 64;
    int Kf = K >> 5;

    f32x4 acc[4][4];
    #pragma unroll
    for (int i = 0; i < 4; i++)
        #pragma unroll
        for (int j = 0; j < 4; j++) acc[i][j] = (f32x4){0.f, 0.f, 0.f, 0.f};

    int sg = ((tid & 3) ^ ((tid >> 3) & 3)) * 8;
    const unsigned short* pa = A + (long)(m0 + (tid >> 2)) * K + sg;
    const unsigned short* pbk = Bpk + ((long)(n0 >> 4) * Kf * 64 + lane) * 8;

#define STAGE(buf, kt) do { \
    _Pragma("unroll") \
    for (int c = 0; c < 4; c++) \
        gload16(pa + (long)(c * 64) * K + (kt), &As[buf][c * 2048 + tid * 8]); \
} while (0)

    STAGE(0, 0);
    __syncthreads();

    int cur = 0;
    int acol = (g ^ ((li >> 1) & 3)) * 8;
    for (int t = 0; t < Kf; t++) {
        bf16x8 bfr[4];
        #pragma unroll
        for (int j = 0; j < 4; j++)
            bfr[j] = *(const bf16x8*)(pbk + ((long)j * Kf + t) * 512);
        if (t + 1 < Kf) STAGE(cur ^ 1, (t + 1) << 5);
        const unsigned short* ab = &As[cur][(wid * 64 + li) * 32 + acol];
        bf16x8 af[4];
        #pragma unroll
        for (int i = 0; i < 4; i++) af[i] = *(const bf16x8*)(ab + i * 512);
        __builtin_amdgcn_s_setprio(1);
        #pragma unroll
        for (int i = 0; i < 4; i++)
            #pragma unroll
            for (int j = 0; j < 4; j++)
                acc[i][j] = __builtin_amdgcn_mfma_f32_16x16x32_bf16(af[i], bfr[j], acc[i][j], 0, 0, 0);
        __builtin_amdgcn_s_setprio(0);
        if (t + 1 < Kf) {
            __syncthreads();
            cur ^= 1;
        }
    }
#undef STAGE

    #pragma unroll
    for (int i = 0; i < 4; i++) {
        int rowb = m0 + wid * 64 + i * 16 + g * 4;
        #pragma unroll
        for (int j = 0; j < 4; j++) {
            int col = n0 + j * 16 + li;
            #pragma unroll
            for (int r = 0; r < 4; r++) {
                float v = acc[i][j][r];
                int rr = rowb + r;
                if (EPI == 0) {
                    int sec = col / 192;
                    int cc = col - sec * 192;
                    int h = cc >> 5, d = cc & 31;
                    int w = rr >> 7, n = rr & 127;
                    outU[(((long)sec * 3072 + w * 6 + h) * 128 + n) * 32 + d] = f2bf(v);
                } else {
                    int w = rr >> 7, tt = rr & 127;
                    int bb2 = w >> 8, rem = w & 255;
                    int dw = rem >> 6, hw = (rem >> 3) & 7, ww = rem & 7;
                    int td = tt >> 6, th = (tt >> 3) & 7, tw = tt & 7;
                    int d = (dw * 2 + td + 1) & 7;
                    int hh = (hw * 8 + th + 4) & 63;
                    int wo = (ww * 8 + tw + 4) & 63;
                    long src = ((long)((bb2 * 8 + d) * 64 + hh) * 64 + wo) * 192 + col;
                    outU[src] = f2bf(addsrc[src] + v + bias[col]);   // x1 in bf16
                }
            }
        }
    }
}

// ---------------- fused LN2 + MLP1 + GELU + MLP2 + residual (x1 in bf16) ----------------
// One block = 64 token rows, 512 threads (8 waves). LDS in MFMA-FRAGMENT-PACKED layout.
// Register prefetch pipeline: W1 frags double-buffered (chunk-0 loads hide under LN;
// chunk-i+1 loads hide under GEMM2). W2 frags fully hoisted (all 4 kf) after GEMM1 ->
// GEMM2 is global-load-free.
__global__ __launch_bounds__(512, 4) void k_mlp(const unsigned short* __restrict__ x1,
                                                const float* __restrict__ g2, const float* __restrict__ b2,
                                                const unsigned short* __restrict__ wf1pk,
                                                const unsigned short* __restrict__ wf2pk,
                                                const float* __restrict__ bf1v, const float* __restrict__ bf2v,
                                                float* __restrict__ out) {
    __shared__ __align__(16) unsigned short A_s[24 * 512];  // 24576 B
    __shared__ __align__(16) unsigned short H_s[16 * 512];  // 16384 B
    int tid = threadIdx.x;
    int wid = tid >> 6, lane = tid & 63;
    int g = lane >> 4, li = lane & 15;
    long r0 = (long)blockIdx.x * 64;

    // prefetch chunk-0 W1 fragments (completes under the LN stage)
    bf16x8 w1buf[6];
    #pragma unroll
    for (int kf = 0; kf < 6; kf++)
        w1buf[kf] = *(const bf16x8*)&wf1pk[(((long)wid * 6 + kf) * 64 + lane) * 8];

    // ---- LN2 stage: 8 threads per row, 24 bf16 each; write in packed-frag layout ----
    {
        int row = tid >> 3;
        int c0 = (tid & 7) * 24;
        const unsigned short* xp = x1 + (r0 + row) * 192 + c0;
        float v[24];
        #pragma unroll
        for (int q = 0; q < 3; q++) {
            ush8 f = *(const ush8*)(xp + q * 8);
            #pragma unroll
            for (int e = 0; e < 8; e++) v[q * 8 + e] = bf2f(f[e]);
        }
        float s = 0.f, ss = 0.f;
        #pragma unroll
        for (int q = 0; q < 24; q++) { s += v[q]; ss += v[q] * v[q]; }
        #pragma unroll
        for (int m = 1; m < 8; m <<= 1) { s += __shfl_xor(s, m); ss += __shfl_xor(ss, m); }
        float mu = s * (1.f / 192.f);
        float var = ss * (1.f / 192.f) - mu * mu;
        float inv = rsqrtf(var + 1e-5f);
        ush8 o[3];
        #pragma unroll
        for (int q = 0; q < 24; q++) {
            float gv = g2[c0 + q], bv = b2[c0 + q];
            o[q >> 3][q & 7] = f2bf((v[q] - mu) * inv * gv + bv);
        }
        #pragma unroll
        for (int q = 0; q < 3; q++) {
            int cb = c0 + q * 8;
            int fi = (row >> 4) * 6 + (cb >> 5);            // frag index (mf*6+kf)
            int l2 = (((cb >> 3) & 3) << 4) | (row & 15);   // dest lane in frag
            *(ush8*)&A_s[(fi * 64 + l2) * 8] = o[q];
        }
    }
    __syncthreads();

    int mw = wid >> 2, nw = wid & 3;            // GEMM2 roles: token half, out-col quarter
    int kf2 = wid >> 1;                          // this wave's hidden-frag in GEMM1 output
    int gpos = ((wid & 1) << 1) | (li >> 3);     // position-in-frag for H writes
    int e = li & 7;
    f32x4 acc2[2][3];
    #pragma unroll
    for (int i = 0; i < 2; i++)
        #pragma unroll
        for (int j = 0; j < 3; j++) acc2[i][j] = (f32x4){0.f, 0.f, 0.f, 0.f};

    for (int ch = 0; ch < 6; ch++) {
        // GEMM1: wave owns hidden frag nf = ch*8 + wid (16 cols), all 64 tokens (W1 from regs)
        f32x4 acc1[4];
        #pragma unroll
        for (int i = 0; i < 4; i++) acc1[i] = (f32x4){0.f, 0.f, 0.f, 0.f};
        float bv1 = bf1v[ch * 128 + wid * 16 + li];
        #pragma unroll
        for (int kf = 0; kf < 6; kf++) {
            __builtin_amdgcn_s_setprio(1);
            #pragma unroll
            for (int mf = 0; mf < 4; mf++) {
                bf16x8 a = *(const bf16x8*)&A_s[(((mf * 6 + kf) * 64) + lane) * 8];
                acc1[mf] = __builtin_amdgcn_mfma_f32_16x16x32_bf16(a, w1buf[kf], acc1[mf], 0, 0, 0);
            }
            __builtin_amdgcn_s_setprio(0);
        }
        // full W2 hoist (all 4 kf) -> GEMM2 is global-load-free
        bf16x8 w2p[4][3];
        #pragma unroll
        for (int kf = 0; kf < 4; kf++)
            #pragma unroll
            for (int jf = 0; jf < 3; jf++)
                w2p[kf][jf] = *(const bf16x8*)&wf2pk[(((long)(nw * 3 + jf) * 24 + ch * 4 + kf) * 64 + lane) * 8];
        // bias + gelu + write H chunk in packed-frag layout
        #pragma unroll
        for (int mf = 0; mf < 4; mf++)
            #pragma unroll
            for (int r = 0; r < 4; r++) {
                int l2 = (gpos << 4) | (g * 4 + r);
                H_s[((mf * 4 + kf2) * 64 + l2) * 8 + e] = f2bf(fast_gelu(acc1[mf][r] + bv1));
            }
        __syncthreads();
        // prefetch next chunk's W1 (completes under GEMM2's MFMAs)
        if (ch + 1 < 6) {
            #pragma unroll
            for (int kf = 0; kf < 6; kf++)
                w1buf[kf] = *(const bf16x8*)&wf1pk[(((long)((ch + 1) * 8 + wid) * 6 + kf) * 64 + lane) * 8];
        }
        // GEMM2 partial: out[mw*32.., nw*48..] += H_chunk @ Wf2[:, ch-cols]^T (regs only)
        #pragma unroll
        for (int kf = 0; kf < 4; kf++) {
            bf16x8 hf[2];
            #pragma unroll
            for (int mf = 0; mf < 2; mf++)
                hf[mf] = *(const bf16x8*)&H_s[(((mw * 2 + mf) * 4 + kf) * 64 + lane) * 8];
            __builtin_amdgcn_s_setprio(1);
            #pragma unroll
            for (int mf = 0; mf < 2; mf++)
                #pragma unroll
                for (int jf = 0; jf < 3; jf++)
                    acc2[mf][jf] = __builtin_amdgcn_mfma_f32_16x16x32_bf16(hf[mf], w2p[kf][jf], acc2[mf][jf], 0, 0, 0);
            __builtin_amdgcn_s_setprio(0);
        }
        __syncthreads();
    }

    // epilogue: out = x1 + acc2 + bf2
    #pragma unroll
    for (int mf = 0; mf < 2; mf++) {
        #pragma unroll
        for (int jf = 0; jf < 3; jf++) {
            int col = nw * 48 + jf * 16 + li;
            float bv = bf2v[col];
            #pragma unroll
            for (int r = 0; r < 4; r++) {
                int row = mw * 32 + mf * 16 + g * 4 + r;
                long idx = (r0 + row) * 192 + col;
                out[idx] = bf2f(x1[idx]) + acc2[mf][jf][r] + bv;
            }
        }
    }
}

// ---------------- attention: one block per (window, head) ----------------
__global__ __launch_bounds__(256, 3) void k_attn(const unsigned short* __restrict__ qkv,
                                                 const float* __restrict__ bmt,
                                                 unsigned short* __restrict__ attnout) {
    __shared__ __align__(16) char smem[42496];
    unsigned short* q_s  = (unsigned short*)smem;
    unsigned short* k_s  = q_s + 128 * 36;
    unsigned short* p_s  = (unsigned short*)smem;
    unsigned short* vt_s = (unsigned short*)(smem + 33792);

    int w = blockIdx.x, h = blockIdx.y;
    int tid = threadIdx.x, wid = tid >> 6, lane = tid & 63, g = lane >> 4, li = lane & 15;
    int rem = w & 255;
    int dw = rem >> 6, hw = (rem >> 3) & 7, ww = rem & 7;
    int variant = (dw == 3 ? 1 : 0) | (hw == 7 ? 2 : 0) | (ww == 7 ? 4 : 0);
    const float* bm = bmt + (long)(h * 8 + variant) * 16384;

    const unsigned short* qg = qkv + (long)(w * 6 + h) * 4096;
    const unsigned short* kg = qg + (long)3072 * 4096;
    const unsigned short* vg = qg + (long)6144 * 4096;

    #pragma unroll
    for (int c = tid; c < 512; c += 256) {
        int row = c >> 2, sub = c & 3;
        *(uint4*)&q_s[row * 36 + sub * 8] = *(const uint4*)&qg[row * 32 + sub * 8];
        *(uint4*)&k_s[row * 36 + sub * 8] = *(const uint4*)&kg[row * 32 + sub * 8];
    }
    {
        int key = tid >> 1, d0 = (tid & 1) * 16;
        const unsigned short* vp = vg + key * 32 + d0;
        ush8 va = *(const ush8*)vp, vb = *(const ush8*)(vp + 8);
        #pragma unroll
        for (int dd = 0; dd < 8; dd++) vt_s[(d0 + dd) * 136 + key] = va[dd];
        #pragma unroll
        for (int dd = 0; dd < 8; dd++) vt_s[(d0 + 8 + dd) * 136 + key] = vb[dd];
    }
    __syncthreads();

    f32x4 s[2][8];
    #pragma unroll
    for (int i = 0; i < 2; i++)
        #pragma unroll
        for (int j = 0; j < 8; j++) s[i][j] = (f32x4){0.f, 0.f, 0.f, 0.f};
    bf16x8 qa[2];
    #pragma unroll
    for (int fm = 0; fm < 2; fm++)
        qa[fm] = *(const bf16x8*)&q_s[(wid * 32 + fm * 16 + li) * 36 + g * 8];
    __builtin_amdgcn_s_setprio(1);
    #pragma unroll
    for (int fn = 0; fn < 8; fn++) {
        bf16x8 kb = *(const bf16x8*)&k_s[(fn * 16 + li) * 36 + g * 8];
        s[0][fn] = __builtin_amdgcn_mfma_f32_16x16x32_bf16(qa[0], kb, s[0][fn], 0, 0, 0);
        s[1][fn] = __builtin_amdgcn_mfma_f32_16x16x32_bf16(qa[1], kb, s[1][fn], 0, 0, 0);
    }
    __builtin_amdgcn_s_setprio(0);
    __syncthreads();

    #pragma unroll
    for (int fm = 0; fm < 2; fm++) {
        #pragma unroll
        for (int r = 0; r < 4; r++) {
            int i = wid * 32 + fm * 16 + g * 4 + r;
            const float4 b0 = *(const float4*)&bm[i * 128 + li * 8];
            const float4 b1 = *(const float4*)&bm[i * 128 + li * 8 + 4];
            float vals[8];
            vals[0] = s[fm][0][r] + b0.x; vals[1] = s[fm][1][r] + b0.y;
            vals[2] = s[fm][2][r] + b0.z; vals[3] = s[fm][3][r] + b0.w;
            vals[4] = s[fm][4][r] + b1.x; vals[5] = s[fm][5][r] + b1.y;
            vals[6] = s[fm][6][r] + b1.z; vals[7] = s[fm][7][r] + b1.w;
            float mx = fmaxf(fmaxf(fmaxf(vals[0], vals[1]), fmaxf(vals[2], vals[3])),
                             fmaxf(fmaxf(vals[4], vals[5]), fmaxf(vals[6], vals[7])));
            #pragma unroll
            for (int m = 1; m < 16; m <<= 1) mx = fmaxf(mx, __shfl_xor(mx, m, 16));
            float sum = 0.f;
            #pragma unroll
            for (int fn = 0; fn < 8; fn++) { vals[fn] = __expf(vals[fn] - mx); sum += vals[fn]; }
            #pragma unroll
            for (int m = 1; m < 16; m <<= 1) sum += __shfl_xor(sum, m, 16);
            float inv = __builtin_amdgcn_rcpf(sum);
            #pragma unroll
            for (int fn = 0; fn < 8; fn++)
                p_s[i * 132 + fn * 16 + li] = f2bf(vals[fn] * inv);
        }
    }

    f32x4 o[2][2];
    #pragma unroll
    for (int i = 0; i < 2; i++)
        #pragma unroll
        for (int j = 0; j < 2; j++) o[i][j] = (f32x4){0.f, 0.f, 0.f, 0.f};
    __builtin_amdgcn_s_setprio(1);
    #pragma unroll
    for (int ks = 0; ks < 4; ks++) {
        bf16x8 pa[2];
        #pragma unroll
        for (int fm = 0; fm < 2; fm++)
            pa[fm] = *(const bf16x8*)&p_s[(wid * 32 + fm * 16 + li) * 132 + ks * 32 + g * 8];
        #pragma unroll
        for (int fn = 0; fn < 2; fn++) {
            bf16x8 vb = *(const bf16x8*)&vt_s[(fn * 16 + li) * 136 + ks * 32 + g * 8];
            o[0][fn] = __builtin_amdgcn_mfma_f32_16x16x32_bf16(pa[0], vb, o[0][fn], 0, 0, 0);
            o[1][fn] = __builtin_amdgcn_mfma_f32_16x16x32_bf16(pa[1], vb, o[1][fn], 0, 0, 0);
        }
    }
    __builtin_amdgcn_s_setprio(0);

    unsigned short* op = attnout + (long)w * 128 * 192 + h * 32;
    #pragma unroll
    for (int fm = 0; fm < 2; fm++) {
        #pragma unroll
        for (int fn = 0; fn < 2; fn++) {
            #pragma unroll
            for (int r = 0; r < 4; r++) {
                int n = wid * 32 + fm * 16 + g * 4 + r;
                op[(long)n * 192 + fn * 16 + li] = f2bf(o[fm][fn][r]);
            }
        }
    }
}

// ---------------- host ----------------
extern "C" void kernel_launch(void* const* d_in, const int* in_sizes, int n_in,
                              void* d_out, int out_size, void* d_ws, size_t ws_size,
                              hipStream_t stream) {
    const float* x   = (const float*)d_in[0];
    const float* g1  = (const float*)d_in[1];
    const float* b1  = (const float*)d_in[2];
    const float* Wq  = (const float*)d_in[3];
    const float* Wkv = (const float*)d_in[4];
    const float* rpb = (const float*)d_in[5];
    const float* Wp  = (const float*)d_in[6];
    const float* bp  = (const float*)d_in[7];
    const float* g2  = (const float*)d_in[8];
    const float* b2  = (const float*)d_in[9];
    const float* Wf1 = (const float*)d_in[10];
    const float* bf1 = (const float*)d_in[11];
    const float* Wf2 = (const float*)d_in[12];
    const float* bf2 = (const float*)d_in[13];
    float* out = (float*)d_out;
    char* ws = (char*)d_ws;

    unsigned short* wpk  = (unsigned short*)ws;               // 884736 B
    float* bmt           = (float*)(ws + 917504);             // 3145728 B -> ends 4063232
    unsigned short* xw   = (unsigned short*)(ws + 4194304);   // 25165824 B -> ends 29360128
    unsigned short* qkvb = (unsigned short*)(ws + 29360128);  // 75497472 B -> ends 104857600
    unsigned short* attb = xw;                                // reuse after QKV consumed
    unsigned short* x1b  = (unsigned short*)(ws + 29360128);  // 25165824 B bf16 (reuses qkv region)

    const unsigned short* qkvpk = wpk;
    const unsigned short* wppk  = wpk + 110592;
    const unsigned short* wf1pk = wpk + 147456;
    const unsigned short* wf2pk = wpk + 294912;

    k_pack<<<216, 256, 0, stream>>>(Wq, Wkv, Wp, Wf1, Wf2, wpk);
    k_bmt<<<3072, 256, 0, stream>>>(rpb, bmt);
    k_ln<<<16384, 256, 0, stream>>>(x, g1, b1, xw);
    k_gemm<0><<<dim3(9, 256), 256, 0, stream>>>(xw, qkvpk, 192, nullptr, nullptr, qkvb);
    k_attn<<<dim3(512, 6), 256, 0, stream>>>(qkvb, bmt, attb);
    k_gemm<1><<<dim3(3, 256), 256, 0, stream>>>(attb, wppk, 192, bp, x, x1b);
    k_mlp<<<1024, 512, 0, stream>>>(x1b, g2, b2, wf1pk, wf2pk, bf1, bf2, out);
}

// Round 18
// 204.009 us; speedup vs baseline: 1.0955x; 1.0491x over previous
//
#include <hip/hip_runtime.h>
#include <cstdint>

#define DEVI static __device__ __forceinline__

typedef __attribute__((ext_vector_type(8))) short bf16x8;
typedef __attribute__((ext_vector_type(4))) float f32x4;
typedef __attribute__((ext_vector_type(8))) unsigned short ush8;

DEVI unsigned short f2bf(float f) {
    unsigned u = __float_as_uint(f);
    u += 0x7fff + ((u >> 16) & 1);
    return (unsigned short)(u >> 16);
}
DEVI float bf2f(unsigned short h) { return __uint_as_float(((unsigned)h) << 16); }

DEVI void gload16(const void* g, void* l) {
    __builtin_amdgcn_global_load_lds((const __attribute__((address_space(1))) void*)g,
                                     (__attribute__((address_space(3))) void*)l, 16, 0, 0);
}

DEVI float fast_gelu(float x) {
    // tanh-approx GELU via raw v_rcp_f32 (no -ffast-math; '/' would expand to ~12-op exact div)
    float z = 1.5957691216057308f * (x + 0.044715f * x * x * x);
    return x - x * __builtin_amdgcn_rcpf(__expf(z) + 1.f);
}

// ---------------- weight pack: fp32 -> bf16 in MFMA-fragment order ----------------
__global__ __launch_bounds__(256) void k_pack(const float* __restrict__ Wq, const float* __restrict__ Wkv,
                                              const float* __restrict__ Wp, const float* __restrict__ Wf1,
                                              const float* __restrict__ Wf2, unsigned short* __restrict__ dst) {
    int t = blockIdx.x * 256 + threadIdx.x;
    if (t >= 55296) return;
    int c, base, K;
    const float* src = nullptr;
    if (t < 13824)      { c = t;         base = 0;      K = 192; }
    else if (t < 18432) { c = t - 13824; base = 110592; K = 192; src = Wp; }
    else if (t < 36864) { c = t - 18432; base = 147456; K = 192; src = Wf1; }
    else                { c = t - 36864; base = 294912; K = 768; src = Wf2; }
    int lane = c & 63, fk = c >> 6, Kf = K >> 5;
    int kf = fk % Kf, nf = fk / Kf;
    int row = nf * 16 + (lane & 15), col = kf * 32 + (lane >> 4) * 8;
    ush8 o;
    if (t < 13824) {
        if (row < 192) {
            #pragma unroll
            for (int q = 0; q < 8; q++) o[q] = f2bf(Wq[row * 192 + col + q] * 0.17677669529663687f);
        } else {
            #pragma unroll
            for (int q = 0; q < 8; q++) o[q] = f2bf(Wkv[(row - 192) * 192 + col + q]);
        }
    } else {
        #pragma unroll
        for (int q = 0; q < 8; q++) o[q] = f2bf(src[(long)row * K + col + q]);
    }
    *(ush8*)&dst[base + c * 8] = o;
}

// ---------------- fused bias+mask table: [6 heads][8 variants][128 i][16 li][8 fn] f32 ----------------
__global__ __launch_bounds__(256) void k_bmt(const float* __restrict__ rpb, float* __restrict__ bmt) {
    int t = blockIdx.x * 256 + threadIdx.x;  // 6 * 131072
    int h = t >> 17;
    int r = t & 131071;
    int v = r >> 14;
    int ij = r & 16383;
    int i = ij >> 7, li = (ij >> 3) & 15, fn = ij & 7;
    int j = fn * 16 + li;
    int tdi = i >> 6, thi = (i >> 3) & 7, twi = i & 7;
    int tdj = j >> 6, thj = (j >> 3) & 7, twj = j & 7;
    int idx = ((tdi - tdj + 1) * 15 + (thi - thj + 7)) * 15 + (twi - twj + 7);
    float b = rpb[idx * 6 + h];
    int dwb = v & 1, hwb = (v >> 1) & 1, wwb = (v >> 2) & 1;
    int ri = (dwb ? 1 + tdi : 0) * 9 + (hwb ? (thi < 4 ? 1 : 2) : 0) * 3 + (wwb ? (twi < 4 ? 1 : 2) : 0);
    int rj = (dwb ? 1 + tdj : 0) * 9 + (hwb ? (thj < 4 ? 1 : 2) : 0) * 3 + (wwb ? (twj < 4 ? 1 : 2) : 0);
    if (ri != rj) b -= 100.f;
    bmt[(long)(h * 8 + v) * 16384 + i * 128 + li * 8 + fn] = b;
}

// ---------------- LayerNorm fused with roll+window gather ----------------
__global__ __launch_bounds__(256) void k_ln(const float* __restrict__ x, const float* __restrict__ g,
                                            const float* __restrict__ b, unsigned short* __restrict__ outp) {
    int wid = threadIdx.x >> 6, lane = threadIdx.x & 63;
    int t = blockIdx.x * 4 + wid;
    int w = t >> 7, tt = t & 127;
    int bb = w >> 8, rem = w & 255;
    int dw = rem >> 6, hw = (rem >> 3) & 7, ww = rem & 7;
    int td = tt >> 6, th = (tt >> 3) & 7, tw = tt & 7;
    int d = (dw * 2 + td + 1) & 7;
    int hh = (hw * 8 + th + 4) & 63;
    int wo = (ww * 8 + tw + 4) & 63;
    long src = (long)((bb * 8 + d) * 64 + hh) * 64 + wo;
    const float* xp = x + src * 192;
    float v0 = xp[lane], v1 = xp[lane + 64], v2 = xp[lane + 128];
    float s = v0 + v1 + v2, ss = v0 * v0 + v1 * v1 + v2 * v2;
    #pragma unroll
    for (int m = 32; m; m >>= 1) { s += __shfl_xor(s, m); ss += __shfl_xor(ss, m); }
    float mu = s * (1.f / 192.f);
    float var = ss * (1.f / 192.f) - mu * mu;
    float inv = rsqrtf(var + 1e-5f);
    unsigned short* op = outp + (long)t * 192;
    op[lane]       = f2bf((v0 - mu) * inv * g[lane]       + b[lane]);
    op[lane + 64]  = f2bf((v1 - mu) * inv * g[lane + 64]  + b[lane + 64]);
    op[lane + 128] = f2bf((v2 - mu) * inv * g[lane + 128] + b[lane + 128]);
}

// ---------------- bf16 MFMA GEMM: C[M,N] = A[M,K] @ B[N,K]^T, B in packed-frag form ----------------
// EPI: 1=proj + window-reverse + residual -> x1 bf16
template <int EPI>
__global__ __launch_bounds__(256, 4) void k_gemm(const unsigned short* __restrict__ A,
                                                 const unsigned short* __restrict__ Bpk, int K,
                                                 const float* __restrict__ bias,
                                                 const float* __restrict__ addsrc,
                                                 unsigned short* __restrict__ outU) {
    __shared__ __align__(16) unsigned short As[2][256 * 32];
    int tid = threadIdx.x;
    int wid = tid >> 6, lane = tid & 63;
    int g = lane >> 4, li = lane & 15;
    int m0 = blockIdx.y * 256, n0 = blockIdx.x * 64;
    int Kf = K >> 5;

    f32x4 acc[4][4];
    #pragma unroll
    for (int i = 0; i < 4; i++)
        #pragma unroll
        for (int j = 0; j < 4; j++) acc[i][j] = (f32x4){0.f, 0.f, 0.f, 0.f};

    int sg = ((tid & 3) ^ ((tid >> 3) & 3)) * 8;
    const unsigned short* pa = A + (long)(m0 + (tid >> 2)) * K + sg;
    const unsigned short* pbk = Bpk + ((long)(n0 >> 4) * Kf * 64 + lane) * 8;

#define STAGE(buf, kt) do { \
    _Pragma("unroll") \
    for (int c = 0; c < 4; c++) \
        gload16(pa + (long)(c * 64) * K + (kt), &As[buf][c * 2048 + tid * 8]); \
} while (0)

    STAGE(0, 0);
    __syncthreads();

    int cur = 0;
    int acol = (g ^ ((li >> 1) & 3)) * 8;
    for (int t = 0; t < Kf; t++) {
        bf16x8 bfr[4];
        #pragma unroll
        for (int j = 0; j < 4; j++)
            bfr[j] = *(const bf16x8*)(pbk + ((long)j * Kf + t) * 512);
        if (t + 1 < Kf) STAGE(cur ^ 1, (t + 1) << 5);
        const unsigned short* ab = &As[cur][(wid * 64 + li) * 32 + acol];
        bf16x8 af[4];
        #pragma unroll
        for (int i = 0; i < 4; i++) af[i] = *(const bf16x8*)(ab + i * 512);
        __builtin_amdgcn_s_setprio(1);
        #pragma unroll
        for (int i = 0; i < 4; i++)
            #pragma unroll
            for (int j = 0; j < 4; j++)
                acc[i][j] = __builtin_amdgcn_mfma_f32_16x16x32_bf16(af[i], bfr[j], acc[i][j], 0, 0, 0);
        __builtin_amdgcn_s_setprio(0);
        if (t + 1 < Kf) {
            __syncthreads();
            cur ^= 1;
        }
    }
#undef STAGE

    #pragma unroll
    for (int i = 0; i < 4; i++) {
        int rowb = m0 + wid * 64 + i * 16 + g * 4;
        #pragma unroll
        for (int j = 0; j < 4; j++) {
            int col = n0 + j * 16 + li;
            #pragma unroll
            for (int r = 0; r < 4; r++) {
                float v = acc[i][j][r];
                int rr = rowb + r;
                {
                    int w = rr >> 7, tt = rr & 127;
                    int bb2 = w >> 8, rem = w & 255;
                    int dw = rem >> 6, hw = (rem >> 3) & 7, ww = rem & 7;
                    int td = tt >> 6, th = (tt >> 3) & 7, tw = tt & 7;
                    int d = (dw * 2 + td + 1) & 7;
                    int hh = (hw * 8 + th + 4) & 63;
                    int wo = (ww * 8 + tw + 4) & 63;
                    long src = ((long)((bb2 * 8 + d) * 64 + hh) * 64 + wo) * 192 + col;
                    outU[src] = f2bf(addsrc[src] + v + bias[col]);   // x1 in bf16
                }
            }
        }
    }
}

// ---------------- fused LN2 + MLP1 + GELU + MLP2 + residual (x1 in bf16) ----------------
// One block = 64 token rows, 512 threads (8 waves). LDS in MFMA-FRAGMENT-PACKED layout
// (frag = 64 lanes x 16B contiguous -> conflict-free 1KB wave reads). 40KB LDS.
__global__ __launch_bounds__(512, 4) void k_mlp(const unsigned short* __restrict__ x1,
                                                const float* __restrict__ g2, const float* __restrict__ b2,
                                                const unsigned short* __restrict__ wf1pk,
                                                const unsigned short* __restrict__ wf2pk,
                                                const float* __restrict__ bf1v, const float* __restrict__ bf2v,
                                                float* __restrict__ out) {
    __shared__ __align__(16) unsigned short A_s[24 * 512];  // 24576 B
    __shared__ __align__(16) unsigned short H_s[16 * 512];  // 16384 B
    int tid = threadIdx.x;
    int wid = tid >> 6, lane = tid & 63;
    int g = lane >> 4, li = lane & 15;
    long r0 = (long)blockIdx.x * 64;

    // ---- LN2 stage: 8 threads per row, 24 bf16 each; write in packed-frag layout ----
    {
        int row = tid >> 3;
        int c0 = (tid & 7) * 24;
        const unsigned short* xp = x1 + (r0 + row) * 192 + c0;
        float v[24];
        #pragma unroll
        for (int q = 0; q < 3; q++) {
            ush8 f = *(const ush8*)(xp + q * 8);
            #pragma unroll
            for (int e = 0; e < 8; e++) v[q * 8 + e] = bf2f(f[e]);
        }
        float s = 0.f, ss = 0.f;
        #pragma unroll
        for (int q = 0; q < 24; q++) { s += v[q]; ss += v[q] * v[q]; }
        #pragma unroll
        for (int m = 1; m < 8; m <<= 1) { s += __shfl_xor(s, m); ss += __shfl_xor(ss, m); }
        float mu = s * (1.f / 192.f);
        float var = ss * (1.f / 192.f) - mu * mu;
        float inv = rsqrtf(var + 1e-5f);
        ush8 o[3];
        #pragma unroll
        for (int q = 0; q < 24; q++) {
            float gv = g2[c0 + q], bv = b2[c0 + q];
            o[q >> 3][q & 7] = f2bf((v[q] - mu) * inv * gv + bv);
        }
        #pragma unroll
        for (int q = 0; q < 3; q++) {
            int cb = c0 + q * 8;
            int fi = (row >> 4) * 6 + (cb >> 5);            // frag index (mf*6+kf)
            int l2 = (((cb >> 3) & 3) << 4) | (row & 15);   // dest lane in frag
            *(ush8*)&A_s[(fi * 64 + l2) * 8] = o[q];
        }
    }
    __syncthreads();

    int mw = wid >> 2, nw = wid & 3;            // GEMM2 roles: token half, out-col quarter
    int kf2 = wid >> 1;                          // this wave's hidden-frag in GEMM1 output
    int gpos = ((wid & 1) << 1) | (li >> 3);     // position-in-frag for H writes
    int e = li & 7;
    f32x4 acc2[2][3];
    #pragma unroll
    for (int i = 0; i < 2; i++)
        #pragma unroll
        for (int j = 0; j < 3; j++) acc2[i][j] = (f32x4){0.f, 0.f, 0.f, 0.f};

    for (int ch = 0; ch < 6; ch++) {
        // GEMM1: wave owns hidden frag nf = ch*8 + wid (16 cols), all 64 tokens
        f32x4 acc1[4];
        #pragma unroll
        for (int i = 0; i < 4; i++) acc1[i] = (f32x4){0.f, 0.f, 0.f, 0.f};
        int nf = ch * 8 + wid;
        float bv1 = bf1v[ch * 128 + wid * 16 + li];
        #pragma unroll
        for (int kf = 0; kf < 6; kf++) {
            bf16x8 b = *(const bf16x8*)&wf1pk[(((long)nf * 6 + kf) * 64 + lane) * 8];
            __builtin_amdgcn_s_setprio(1);
            #pragma unroll
            for (int mf = 0; mf < 4; mf++) {
                bf16x8 a = *(const bf16x8*)&A_s[(((mf * 6 + kf) * 64) + lane) * 8];
                acc1[mf] = __builtin_amdgcn_mfma_f32_16x16x32_bf16(a, b, acc1[mf], 0, 0, 0);
            }
            __builtin_amdgcn_s_setprio(0);
        }
        // hoist W2 loads for kf=0,1 across the barrier
        bf16x8 w2p[2][3];
        #pragma unroll
        for (int kf = 0; kf < 2; kf++)
            #pragma unroll
            for (int jf = 0; jf < 3; jf++)
                w2p[kf][jf] = *(const bf16x8*)&wf2pk[(((long)(nw * 3 + jf) * 24 + ch * 4 + kf) * 64 + lane) * 8];
        // bias + gelu + write H chunk in packed-frag layout
        #pragma unroll
        for (int mf = 0; mf < 4; mf++)
            #pragma unroll
            for (int r = 0; r < 4; r++) {
                int l2 = (gpos << 4) | (g * 4 + r);
                H_s[((mf * 4 + kf2) * 64 + l2) * 8 + e] = f2bf(fast_gelu(acc1[mf][r] + bv1));
            }
        __syncthreads();
        // GEMM2 partial: out[mw*32.., nw*48..] += H_chunk @ Wf2[:, ch-cols]^T
        #pragma unroll
        for (int kf = 0; kf < 4; kf++) {
            bf16x8 hf[2], bf[3];
            #pragma unroll
            for (int mf = 0; mf < 2; mf++)
                hf[mf] = *(const bf16x8*)&H_s[(((mw * 2 + mf) * 4 + kf) * 64 + lane) * 8];
            if (kf < 2) {
                #pragma unroll
                for (int jf = 0; jf < 3; jf++) bf[jf] = w2p[kf][jf];
            } else {
                #pragma unroll
                for (int jf = 0; jf < 3; jf++)
                    bf[jf] = *(const bf16x8*)&wf2pk[(((long)(nw * 3 + jf) * 24 + ch * 4 + kf) * 64 + lane) * 8];
            }
            __builtin_amdgcn_s_setprio(1);
            #pragma unroll
            for (int mf = 0; mf < 2; mf++)
                #pragma unroll
                for (int jf = 0; jf < 3; jf++)
                    acc2[mf][jf] = __builtin_amdgcn_mfma_f32_16x16x32_bf16(hf[mf], bf[jf], acc2[mf][jf], 0, 0, 0);
            __builtin_amdgcn_s_setprio(0);
        }
        __syncthreads();
    }

    // epilogue: out = x1 + acc2 + bf2
    #pragma unroll
    for (int mf = 0; mf < 2; mf++) {
        #pragma unroll
        for (int jf = 0; jf < 3; jf++) {
            int col = nw * 48 + jf * 16 + li;
            float bv = bf2v[col];
            #pragma unroll
            for (int r = 0; r < 4; r++) {
                int row = mw * 32 + mf * 16 + g * 4 + r;
                long idx = (r0 + row) * 192 + col;
                out[idx] = bf2f(x1[idx]) + acc2[mf][jf][r] + bv;
            }
        }
    }
}

// ---------------- attention with fused QKV: one block per (head, window) ----------------
// Stages the window's xw tile (128x192 -> padded [128][200] LDS), computes q/k/v for this
// head with MFMA from packed qkv weight frags (L2-hot), scatters into q_s/k_s/vt_s, then
// runs QK^T + bias/mask softmax + PV as before. p_s overlays the dead xw tile.
__global__ __launch_bounds__(256, 2) void k_attn(const unsigned short* __restrict__ xw,
                                                 const unsigned short* __restrict__ qkvpk,
                                                 const float* __restrict__ bmt,
                                                 unsigned short* __restrict__ attnout) {
    __shared__ __align__(16) char smem[78336];
    unsigned short* xw_s = (unsigned short*)smem;            // [128][200] = 51200B, dead after QKV
    unsigned short* p_s  = (unsigned short*)smem;            // [128][132] = 33792B, overlays xw_s
    unsigned short* q_s  = (unsigned short*)(smem + 51200);  // [128][36]  = 9216B
    unsigned short* k_s  = (unsigned short*)(smem + 60416);  // [128][36]  = 9216B
    unsigned short* vt_s = (unsigned short*)(smem + 69632);  // [32][136]  = 8704B

    int h = blockIdx.x, w = blockIdx.y;
    int tid = threadIdx.x, wid = tid >> 6, lane = tid & 63, g = lane >> 4, li = lane & 15;
    int rem = w & 255;
    int dw = rem >> 6, hw = (rem >> 3) & 7, ww = rem & 7;
    int variant = (dw == 3 ? 1 : 0) | (hw == 7 ? 2 : 0) | (ww == 7 ? 4 : 0);
    const float* bm = bmt + (long)(h * 8 + variant) * 16384;

    // ---- stage xw tile [128][192] -> padded LDS [128][200] (2-way-free frag reads) ----
    {
        int r = tid >> 1, c0 = (tid & 1) * 96;
        const unsigned short* src = xw + ((long)w * 128 + r) * 192 + c0;
        #pragma unroll
        for (int j = 0; j < 12; j++)
            *(uint4*)&xw_s[r * 200 + c0 + j * 8] = *(const uint4*)(src + j * 8);
    }
    __syncthreads();

    // ---- QKV: wave wid owns tokens wid*32..+31; out frags j: {q0,q1,k0,k1,v0,v1} ----
    f32x4 qk[2][6];
    #pragma unroll
    for (int i = 0; i < 2; i++)
        #pragma unroll
        for (int j = 0; j < 6; j++) qk[i][j] = (f32x4){0.f, 0.f, 0.f, 0.f};
    for (int kf = 0; kf < 6; kf++) {
        bf16x8 a0 = *(const bf16x8*)&xw_s[(wid * 32 + li) * 200 + kf * 32 + g * 8];
        bf16x8 a1 = *(const bf16x8*)&xw_s[(wid * 32 + 16 + li) * 200 + kf * 32 + g * 8];
        __builtin_amdgcn_s_setprio(1);
        #pragma unroll
        for (int j = 0; j < 6; j++) {
            int nf = (j >> 1) * 12 + 2 * h + (j & 1);
            bf16x8 b = *(const bf16x8*)&qkvpk[(((long)nf * 6 + kf) * 64 + lane) * 8];
            qk[0][j] = __builtin_amdgcn_mfma_f32_16x16x32_bf16(a0, b, qk[0][j], 0, 0, 0);
            qk[1][j] = __builtin_amdgcn_mfma_f32_16x16x32_bf16(a1, b, qk[1][j], 0, 0, 0);
        }
        __builtin_amdgcn_s_setprio(0);
    }
    // scatter q/k/v into LDS (col=li, row=token g*4+r per C/D layout)
    #pragma unroll
    for (int mf = 0; mf < 2; mf++) {
        int tokb = wid * 32 + mf * 16 + g * 4;
        #pragma unroll
        for (int r = 0; r < 4; r++) {
            int tok = tokb + r;
            q_s[tok * 36 + li]          = f2bf(qk[mf][0][r]);
            q_s[tok * 36 + 16 + li]     = f2bf(qk[mf][1][r]);
            k_s[tok * 36 + li]          = f2bf(qk[mf][2][r]);
            k_s[tok * 36 + 16 + li]     = f2bf(qk[mf][3][r]);
            vt_s[li * 136 + tok]        = f2bf(qk[mf][4][r]);
            vt_s[(16 + li) * 136 + tok] = f2bf(qk[mf][5][r]);
        }
    }
    __syncthreads();   // all xw_s reads done; p_s may overlay from here on

    f32x4 s[2][8];
    #pragma unroll
    for (int i = 0; i < 2; i++)
        #pragma unroll
        for (int j = 0; j < 8; j++) s[i][j] = (f32x4){0.f, 0.f, 0.f, 0.f};
    bf16x8 qa[2];
    #pragma unroll
    for (int fm = 0; fm < 2; fm++)
        qa[fm] = *(const bf16x8*)&q_s[(wid * 32 + fm * 16 + li) * 36 + g * 8];
    __builtin_amdgcn_s_setprio(1);
    #pragma unroll
    for (int fn = 0; fn < 8; fn++) {
        bf16x8 kb = *(const bf16x8*)&k_s[(fn * 16 + li) * 36 + g * 8];
        s[0][fn] = __builtin_amdgcn_mfma_f32_16x16x32_bf16(qa[0], kb, s[0][fn], 0, 0, 0);
        s[1][fn] = __builtin_amdgcn_mfma_f32_16x16x32_bf16(qa[1], kb, s[1][fn], 0, 0, 0);
    }
    __builtin_amdgcn_s_setprio(0);
    __syncthreads();

    #pragma unroll
    for (int fm = 0; fm < 2; fm++) {
        #pragma unroll
        for (int r = 0; r < 4; r++) {
            int i = wid * 32 + fm * 16 + g * 4 + r;
            const float4 b0 = *(const float4*)&bm[i * 128 + li * 8];
            const float4 b1 = *(const float4*)&bm[i * 128 + li * 8 + 4];
            float vals[8];
            vals[0] = s[fm][0][r] + b0.x; vals[1] = s[fm][1][r] + b0.y;
            vals[2] = s[fm][2][r] + b0.z; vals[3] = s[fm][3][r] + b0.w;
            vals[4] = s[fm][4][r] + b1.x; vals[5] = s[fm][5][r] + b1.y;
            vals[6] = s[fm][6][r] + b1.z; vals[7] = s[fm][7][r] + b1.w;
            float mx = fmaxf(fmaxf(fmaxf(vals[0], vals[1]), fmaxf(vals[2], vals[3])),
                             fmaxf(fmaxf(vals[4], vals[5]), fmaxf(vals[6], vals[7])));
            #pragma unroll
            for (int m = 1; m < 16; m <<= 1) mx = fmaxf(mx, __shfl_xor(mx, m, 16));
            float sum = 0.f;
            #pragma unroll
            for (int fn = 0; fn < 8; fn++) { vals[fn] = __expf(vals[fn] - mx); sum += vals[fn]; }
            #pragma unroll
            for (int m = 1; m < 16; m <<= 1) sum += __shfl_xor(sum, m, 16);
            float inv = __builtin_amdgcn_rcpf(sum);
            #pragma unroll
            for (int fn = 0; fn < 8; fn++)
                p_s[i * 132 + fn * 16 + li] = f2bf(vals[fn] * inv);
        }
    }

    f32x4 o[2][2];
    #pragma unroll
    for (int i = 0; i < 2; i++)
        #pragma unroll
        for (int j = 0; j < 2; j++) o[i][j] = (f32x4){0.f, 0.f, 0.f, 0.f};
    __builtin_amdgcn_s_setprio(1);
    #pragma unroll
    for (int ks = 0; ks < 4; ks++) {
        bf16x8 pa[2];
        #pragma unroll
        for (int fm = 0; fm < 2; fm++)
            pa[fm] = *(const bf16x8*)&p_s[(wid * 32 + fm * 16 + li) * 132 + ks * 32 + g * 8];
        #pragma unroll
        for (int fn = 0; fn < 2; fn++) {
            bf16x8 vb = *(const bf16x8*)&vt_s[(fn * 16 + li) * 136 + ks * 32 + g * 8];
            o[0][fn] = __builtin_amdgcn_mfma_f32_16x16x32_bf16(pa[0], vb, o[0][fn], 0, 0, 0);
            o[1][fn] = __builtin_amdgcn_mfma_f32_16x16x32_bf16(pa[1], vb, o[1][fn], 0, 0, 0);
        }
    }
    __builtin_amdgcn_s_setprio(0);

    unsigned short* op = attnout + (long)w * 128 * 192 + h * 32;
    #pragma unroll
    for (int fm = 0; fm < 2; fm++) {
        #pragma unroll
        for (int fn = 0; fn < 2; fn++) {
            #pragma unroll
            for (int r = 0; r < 4; r++) {
                int n = wid * 32 + fm * 16 + g * 4 + r;
                op[(long)n * 192 + fn * 16 + li] = f2bf(o[fm][fn][r]);
            }
        }
    }
}

// ---------------- host ----------------
extern "C" void kernel_launch(void* const* d_in, const int* in_sizes, int n_in,
                              void* d_out, int out_size, void* d_ws, size_t ws_size,
                              hipStream_t stream) {
    const float* x   = (const float*)d_in[0];
    const float* g1  = (const float*)d_in[1];
    const float* b1  = (const float*)d_in[2];
    const float* Wq  = (const float*)d_in[3];
    const float* Wkv = (const float*)d_in[4];
    const float* rpb = (const float*)d_in[5];
    const float* Wp  = (const float*)d_in[6];
    const float* bp  = (const float*)d_in[7];
    const float* g2  = (const float*)d_in[8];
    const float* b2  = (const float*)d_in[9];
    const float* Wf1 = (const float*)d_in[10];
    const float* bf1 = (const float*)d_in[11];
    const float* Wf2 = (const float*)d_in[12];
    const float* bf2 = (const float*)d_in[13];
    float* out = (float*)d_out;
    char* ws = (char*)d_ws;

    unsigned short* wpk  = (unsigned short*)ws;               // 884736 B
    float* bmt           = (float*)(ws + 917504);             // 3145728 B -> ends 4063232
    unsigned short* xw   = (unsigned short*)(ws + 4194304);   // 25165824 B -> ends 29360128
    unsigned short* attb = (unsigned short*)(ws + 29360128);  // 25165824 B -> ends 54525952
    unsigned short* x1b  = (unsigned short*)(ws + 54525952);  // 25165824 B bf16 -> ends 79691776

    const unsigned short* qkvpk = wpk;
    const unsigned short* wppk  = wpk + 110592;
    const unsigned short* wf1pk = wpk + 147456;
    const unsigned short* wf2pk = wpk + 294912;

    k_pack<<<216, 256, 0, stream>>>(Wq, Wkv, Wp, Wf1, Wf2, wpk);
    k_bmt<<<3072, 256, 0, stream>>>(rpb, bmt);
    k_ln<<<16384, 256, 0, stream>>>(x, g1, b1, xw);
    k_attn<<<dim3(6, 512), 256, 0, stream>>>(xw, qkvpk, bmt, attb);
    k_gemm<1><<<dim3(3, 256), 256, 0, stream>>>(attb, wppk, 192, bp, x, x1b);
    k_mlp<<<1024, 512, 0, stream>>>(x1b, g2, b2, wf1pk, wf2pk, bf1, bf2, out);
}

// Round 19
// 190.421 us; speedup vs baseline: 1.1737x; 1.0714x over previous
//
#include <hip/hip_runtime.h>
#include <cstdint>

#define DEVI static __device__ __forceinline__

typedef __attribute__((ext_vector_type(8))) short bf16x8;
typedef __attribute__((ext_vector_type(4))) float f32x4;
typedef __attribute__((ext_vector_type(8))) unsigned short ush8;

DEVI unsigned short f2bf(float f) {
    unsigned u = __float_as_uint(f);
    u += 0x7fff + ((u >> 16) & 1);
    return (unsigned short)(u >> 16);
}
DEVI float bf2f(unsigned short h) { return __uint_as_float(((unsigned)h) << 16); }

DEVI void gload16(const void* g, void* l) {
    __builtin_amdgcn_global_load_lds((const __attribute__((address_space(1))) void*)g,
                                     (__attribute__((address_space(3))) void*)l, 16, 0, 0);
}

DEVI float fast_gelu(float x) {
    // tanh-approx GELU via raw v_rcp_f32 (no -ffast-math; '/' would expand to ~12-op exact div)
    float z = 1.5957691216057308f * (x + 0.044715f * x * x * x);
    return x - x * __builtin_amdgcn_rcpf(__expf(z) + 1.f);
}

// ---------------- weight pack: fp32 -> bf16 in MFMA-fragment order ----------------
__global__ __launch_bounds__(256) void k_pack(const float* __restrict__ Wq, const float* __restrict__ Wkv,
                                              const float* __restrict__ Wp, const float* __restrict__ Wf1,
                                              const float* __restrict__ Wf2, unsigned short* __restrict__ dst) {
    int t = blockIdx.x * 256 + threadIdx.x;
    if (t >= 55296) return;
    int c, base, K;
    const float* src = nullptr;
    if (t < 13824)      { c = t;         base = 0;      K = 192; }
    else if (t < 18432) { c = t - 13824; base = 110592; K = 192; src = Wp; }
    else if (t < 36864) { c = t - 18432; base = 147456; K = 192; src = Wf1; }
    else                { c = t - 36864; base = 294912; K = 768; src = Wf2; }
    int lane = c & 63, fk = c >> 6, Kf = K >> 5;
    int kf = fk % Kf, nf = fk / Kf;
    int row = nf * 16 + (lane & 15), col = kf * 32 + (lane >> 4) * 8;
    ush8 o;
    if (t < 13824) {
        if (row < 192) {
            #pragma unroll
            for (int q = 0; q < 8; q++) o[q] = f2bf(Wq[row * 192 + col + q] * 0.17677669529663687f);
        } else {
            #pragma unroll
            for (int q = 0; q < 8; q++) o[q] = f2bf(Wkv[(row - 192) * 192 + col + q]);
        }
    } else {
        #pragma unroll
        for (int q = 0; q < 8; q++) o[q] = f2bf(src[(long)row * K + col + q]);
    }
    *(ush8*)&dst[base + c * 8] = o;
}

// ---------------- fused bias+mask table: [6 heads][8 variants][128 i][16 li][8 fn] f32 ----------------
__global__ __launch_bounds__(256) void k_bmt(const float* __restrict__ rpb, float* __restrict__ bmt) {
    int t = blockIdx.x * 256 + threadIdx.x;  // 6 * 131072
    int h = t >> 17;
    int r = t & 131071;
    int v = r >> 14;
    int ij = r & 16383;
    int i = ij >> 7, li = (ij >> 3) & 15, fn = ij & 7;
    int j = fn * 16 + li;
    int tdi = i >> 6, thi = (i >> 3) & 7, twi = i & 7;
    int tdj = j >> 6, thj = (j >> 3) & 7, twj = j & 7;
    int idx = ((tdi - tdj + 1) * 15 + (thi - thj + 7)) * 15 + (twi - twj + 7);
    float b = rpb[idx * 6 + h];
    int dwb = v & 1, hwb = (v >> 1) & 1, wwb = (v >> 2) & 1;
    int ri = (dwb ? 1 + tdi : 0) * 9 + (hwb ? (thi < 4 ? 1 : 2) : 0) * 3 + (wwb ? (twi < 4 ? 1 : 2) : 0);
    int rj = (dwb ? 1 + tdj : 0) * 9 + (hwb ? (thj < 4 ? 1 : 2) : 0) * 3 + (wwb ? (twj < 4 ? 1 : 2) : 0);
    if (ri != rj) b -= 100.f;
    bmt[(long)(h * 8 + v) * 16384 + i * 128 + li * 8 + fn] = b;
}

// ---------------- LayerNorm fused with roll+window gather ----------------
__global__ __launch_bounds__(256) void k_ln(const float* __restrict__ x, const float* __restrict__ g,
                                            const float* __restrict__ b, unsigned short* __restrict__ outp) {
    int wid = threadIdx.x >> 6, lane = threadIdx.x & 63;
    int t = blockIdx.x * 4 + wid;
    int w = t >> 7, tt = t & 127;
    int bb = w >> 8, rem = w & 255;
    int dw = rem >> 6, hw = (rem >> 3) & 7, ww = rem & 7;
    int td = tt >> 6, th = (tt >> 3) & 7, tw = tt & 7;
    int d = (dw * 2 + td + 1) & 7;
    int hh = (hw * 8 + th + 4) & 63;
    int wo = (ww * 8 + tw + 4) & 63;
    long src = (long)((bb * 8 + d) * 64 + hh) * 64 + wo;
    const float* xp = x + src * 192;
    float v0 = xp[lane], v1 = xp[lane + 64], v2 = xp[lane + 128];
    float s = v0 + v1 + v2, ss = v0 * v0 + v1 * v1 + v2 * v2;
    #pragma unroll
    for (int m = 32; m; m >>= 1) { s += __shfl_xor(s, m); ss += __shfl_xor(ss, m); }
    float mu = s * (1.f / 192.f);
    float var = ss * (1.f / 192.f) - mu * mu;
    float inv = rsqrtf(var + 1e-5f);
    unsigned short* op = outp + (long)t * 192;
    op[lane]       = f2bf((v0 - mu) * inv * g[lane]       + b[lane]);
    op[lane + 64]  = f2bf((v1 - mu) * inv * g[lane + 64]  + b[lane + 64]);
    op[lane + 128] = f2bf((v2 - mu) * inv * g[lane + 128] + b[lane + 128]);
}

// ---------------- bf16 MFMA GEMM: C[M,N] = A[M,K] @ B[N,K]^T, B in packed-frag form ----------------
// EPI: 1=proj + window-reverse + residual -> x1 bf16
template <int EPI>
__global__ __launch_bounds__(256, 4) void k_gemm(const unsigned short* __restrict__ A,
                                                 const unsigned short* __restrict__ Bpk, int K,
                                                 const float* __restrict__ bias,
                                                 const float* __restrict__ addsrc,
                                                 unsigned short* __restrict__ outU) {
    __shared__ __align__(16) unsigned short As[2][256 * 32];
    int tid = threadIdx.x;
    int wid = tid >> 6, lane = tid & 63;
    int g = lane >> 4, li = lane & 15;
    int m0 = blockIdx.y * 256, n0 = blockIdx.x * 64;
    int Kf = K >> 5;

    f32x4 acc[4][4];
    #pragma unroll
    for (int i = 0; i < 4; i++)
        #pragma unroll
        for (int j = 0; j < 4; j++) acc[i][j] = (f32x4){0.f, 0.f, 0.f, 0.f};

    int sg = ((tid & 3) ^ ((tid >> 3) & 3)) * 8;
    const unsigned short* pa = A + (long)(m0 + (tid >> 2)) * K + sg;
    const unsigned short* pbk = Bpk + ((long)(n0 >> 4) * Kf * 64 + lane) * 8;

#define STAGE(buf, kt) do { \
    _Pragma("unroll") \
    for (int c = 0; c < 4; c++) \
        gload16(pa + (long)(c * 64) * K + (kt), &As[buf][c * 2048 + tid * 8]); \
} while (0)

    STAGE(0, 0);
    __syncthreads();

    int cur = 0;
    int acol = (g ^ ((li >> 1) & 3)) * 8;
    for (int t = 0; t < Kf; t++) {
        bf16x8 bfr[4];
        #pragma unroll
        for (int j = 0; j < 4; j++)
            bfr[j] = *(const bf16x8*)(pbk + ((long)j * Kf + t) * 512);
        if (t + 1 < Kf) STAGE(cur ^ 1, (t + 1) << 5);
        const unsigned short* ab = &As[cur][(wid * 64 + li) * 32 + acol];
        bf16x8 af[4];
        #pragma unroll
        for (int i = 0; i < 4; i++) af[i] = *(const bf16x8*)(ab + i * 512);
        __builtin_amdgcn_s_setprio(1);
        #pragma unroll
        for (int i = 0; i < 4; i++)
            #pragma unroll
            for (int j = 0; j < 4; j++)
                acc[i][j] = __builtin_amdgcn_mfma_f32_16x16x32_bf16(af[i], bfr[j], acc[i][j], 0, 0, 0);
        __builtin_amdgcn_s_setprio(0);
        if (t + 1 < Kf) {
            __syncthreads();
            cur ^= 1;
        }
    }
#undef STAGE

    #pragma unroll
    for (int i = 0; i < 4; i++) {
        int rowb = m0 + wid * 64 + i * 16 + g * 4;
        #pragma unroll
        for (int j = 0; j < 4; j++) {
            int col = n0 + j * 16 + li;
            #pragma unroll
            for (int r = 0; r < 4; r++) {
                float v = acc[i][j][r];
                int rr = rowb + r;
                {
                    int w = rr >> 7, tt = rr & 127;
                    int bb2 = w >> 8, rem = w & 255;
                    int dw = rem >> 6, hw = (rem >> 3) & 7, ww = rem & 7;
                    int td = tt >> 6, th = (tt >> 3) & 7, tw = tt & 7;
                    int d = (dw * 2 + td + 1) & 7;
                    int hh = (hw * 8 + th + 4) & 63;
                    int wo = (ww * 8 + tw + 4) & 63;
                    long src = ((long)((bb2 * 8 + d) * 64 + hh) * 64 + wo) * 192 + col;
                    outU[src] = f2bf(addsrc[src] + v + bias[col]);   // x1 in bf16
                }
            }
        }
    }
}

// ---------------- fused LN2 + MLP1 + GELU + MLP2 + residual (x1 in bf16) ----------------
// One block = 64 token rows, 512 threads (8 waves). LDS in MFMA-FRAGMENT-PACKED layout
// (frag = 64 lanes x 16B contiguous -> conflict-free 1KB wave reads). 40KB LDS.
__global__ __launch_bounds__(512, 4) void k_mlp(const unsigned short* __restrict__ x1,
                                                const float* __restrict__ g2, const float* __restrict__ b2,
                                                const unsigned short* __restrict__ wf1pk,
                                                const unsigned short* __restrict__ wf2pk,
                                                const float* __restrict__ bf1v, const float* __restrict__ bf2v,
                                                float* __restrict__ out) {
    __shared__ __align__(16) unsigned short A_s[24 * 512];  // 24576 B
    __shared__ __align__(16) unsigned short H_s[16 * 512];  // 16384 B
    int tid = threadIdx.x;
    int wid = tid >> 6, lane = tid & 63;
    int g = lane >> 4, li = lane & 15;
    long r0 = (long)blockIdx.x * 64;

    // ---- LN2 stage: 8 threads per row, 24 bf16 each; write in packed-frag layout ----
    {
        int row = tid >> 3;
        int c0 = (tid & 7) * 24;
        const unsigned short* xp = x1 + (r0 + row) * 192 + c0;
        float v[24];
        #pragma unroll
        for (int q = 0; q < 3; q++) {
            ush8 f = *(const ush8*)(xp + q * 8);
            #pragma unroll
            for (int e = 0; e < 8; e++) v[q * 8 + e] = bf2f(f[e]);
        }
        float s = 0.f, ss = 0.f;
        #pragma unroll
        for (int q = 0; q < 24; q++) { s += v[q]; ss += v[q] * v[q]; }
        #pragma unroll
        for (int m = 1; m < 8; m <<= 1) { s += __shfl_xor(s, m); ss += __shfl_xor(ss, m); }
        float mu = s * (1.f / 192.f);
        float var = ss * (1.f / 192.f) - mu * mu;
        float inv = rsqrtf(var + 1e-5f);
        ush8 o[3];
        #pragma unroll
        for (int q = 0; q < 24; q++) {
            float gv = g2[c0 + q], bv = b2[c0 + q];
            o[q >> 3][q & 7] = f2bf((v[q] - mu) * inv * gv + bv);
        }
        #pragma unroll
        for (int q = 0; q < 3; q++) {
            int cb = c0 + q * 8;
            int fi = (row >> 4) * 6 + (cb >> 5);            // frag index (mf*6+kf)
            int l2 = (((cb >> 3) & 3) << 4) | (row & 15);   // dest lane in frag
            *(ush8*)&A_s[(fi * 64 + l2) * 8] = o[q];
        }
    }
    __syncthreads();

    int mw = wid >> 2, nw = wid & 3;            // GEMM2 roles: token half, out-col quarter
    int kf2 = wid >> 1;                          // this wave's hidden-frag in GEMM1 output
    int gpos = ((wid & 1) << 1) | (li >> 3);     // position-in-frag for H writes
    int e = li & 7;
    f32x4 acc2[2][3];
    #pragma unroll
    for (int i = 0; i < 2; i++)
        #pragma unroll
        for (int j = 0; j < 3; j++) acc2[i][j] = (f32x4){0.f, 0.f, 0.f, 0.f};

    for (int ch = 0; ch < 6; ch++) {
        // GEMM1: wave owns hidden frag nf = ch*8 + wid (16 cols), all 64 tokens
        f32x4 acc1[4];
        #pragma unroll
        for (int i = 0; i < 4; i++) acc1[i] = (f32x4){0.f, 0.f, 0.f, 0.f};
        int nf = ch * 8 + wid;
        float bv1 = bf1v[ch * 128 + wid * 16 + li];
        #pragma unroll
        for (int kf = 0; kf < 6; kf++) {
            bf16x8 b = *(const bf16x8*)&wf1pk[(((long)nf * 6 + kf) * 64 + lane) * 8];
            __builtin_amdgcn_s_setprio(1);
            #pragma unroll
            for (int mf = 0; mf < 4; mf++) {
                bf16x8 a = *(const bf16x8*)&A_s[(((mf * 6 + kf) * 64) + lane) * 8];
                acc1[mf] = __builtin_amdgcn_mfma_f32_16x16x32_bf16(a, b, acc1[mf], 0, 0, 0);
            }
            __builtin_amdgcn_s_setprio(0);
        }
        // hoist W2 loads for kf=0,1 across the barrier
        bf16x8 w2p[2][3];
        #pragma unroll
        for (int kf = 0; kf < 2; kf++)
            #pragma unroll
            for (int jf = 0; jf < 3; jf++)
                w2p[kf][jf] = *(const bf16x8*)&wf2pk[(((long)(nw * 3 + jf) * 24 + ch * 4 + kf) * 64 + lane) * 8];
        // bias + gelu + write H chunk in packed-frag layout
        #pragma unroll
        for (int mf = 0; mf < 4; mf++)
            #pragma unroll
            for (int r = 0; r < 4; r++) {
                int l2 = (gpos << 4) | (g * 4 + r);
                H_s[((mf * 4 + kf2) * 64 + l2) * 8 + e] = f2bf(fast_gelu(acc1[mf][r] + bv1));
            }
        __syncthreads();
        // GEMM2 partial: out[mw*32.., nw*48..] += H_chunk @ Wf2[:, ch-cols]^T
        #pragma unroll
        for (int kf = 0; kf < 4; kf++) {
            bf16x8 hf[2], bf[3];
            #pragma unroll
            for (int mf = 0; mf < 2; mf++)
                hf[mf] = *(const bf16x8*)&H_s[(((mw * 2 + mf) * 4 + kf) * 64 + lane) * 8];
            if (kf < 2) {
                #pragma unroll
                for (int jf = 0; jf < 3; jf++) bf[jf] = w2p[kf][jf];
            } else {
                #pragma unroll
                for (int jf = 0; jf < 3; jf++)
                    bf[jf] = *(const bf16x8*)&wf2pk[(((long)(nw * 3 + jf) * 24 + ch * 4 + kf) * 64 + lane) * 8];
            }
            __builtin_amdgcn_s_setprio(1);
            #pragma unroll
            for (int mf = 0; mf < 2; mf++)
                #pragma unroll
                for (int jf = 0; jf < 3; jf++)
                    acc2[mf][jf] = __builtin_amdgcn_mfma_f32_16x16x32_bf16(hf[mf], bf[jf], acc2[mf][jf], 0, 0, 0);
            __builtin_amdgcn_s_setprio(0);
        }
        __syncthreads();
    }

    // epilogue: out = x1 + acc2 + bf2
    #pragma unroll
    for (int mf = 0; mf < 2; mf++) {
        #pragma unroll
        for (int jf = 0; jf < 3; jf++) {
            int col = nw * 48 + jf * 16 + li;
            float bv = bf2v[col];
            #pragma unroll
            for (int r = 0; r < 4; r++) {
                int row = mw * 32 + mf * 16 + g * 4 + r;
                long idx = (r0 + row) * 192 + col;
                out[idx] = bf2f(x1[idx]) + acc2[mf][jf][r] + bv;
            }
        }
    }
}

// ---------------- attention with fused QKV: 3072 blocks, XCD-swizzled ----------------
// Block b -> xcd x=b%8, slot j=b/8 -> window w = x + 8*(j/6), head h = j%6.
// All 6 head-blocks of a window land on the SAME XCD, dispatch-adjacent -> the window's
// xw tile is fetched into that XCD's L2 once and hit 5 more times.
__global__ __launch_bounds__(256, 2) void k_attn(const unsigned short* __restrict__ xw,
                                                 const unsigned short* __restrict__ qkvpk,
                                                 const float* __restrict__ bmt,
                                                 unsigned short* __restrict__ attnout) {
    __shared__ __align__(16) char smem[78336];
    unsigned short* xw_s = (unsigned short*)smem;            // [128][200] = 51200B, dead after QKV
    unsigned short* p_s  = (unsigned short*)smem;            // [128][132] = 33792B, overlays xw_s
    unsigned short* q_s  = (unsigned short*)(smem + 51200);  // [128][36]  = 9216B
    unsigned short* k_s  = (unsigned short*)(smem + 60416);  // [128][36]  = 9216B
    unsigned short* vt_s = (unsigned short*)(smem + 69632);  // [32][136]  = 8704B

    int b = blockIdx.x;
    int xcd = b & 7, j = b >> 3;
    int w = xcd + 8 * (j / 6), h = j % 6;
    int tid = threadIdx.x, wid = tid >> 6, lane = tid & 63, g = lane >> 4, li = lane & 15;
    int rem = w & 255;
    int dw = rem >> 6, hw = (rem >> 3) & 7, ww = rem & 7;
    int variant = (dw == 3 ? 1 : 0) | (hw == 7 ? 2 : 0) | (ww == 7 ? 4 : 0);
    const float* bm = bmt + (long)(h * 8 + variant) * 16384;

    // ---- stage xw tile [128][192] -> padded LDS [128][200] (2-way-free frag reads) ----
    {
        int r = tid >> 1, c0 = (tid & 1) * 96;
        const unsigned short* src = xw + ((long)w * 128 + r) * 192 + c0;
        #pragma unroll
        for (int jj = 0; jj < 12; jj++)
            *(uint4*)&xw_s[r * 200 + c0 + jj * 8] = *(const uint4*)(src + jj * 8);
    }
    __syncthreads();

    // ---- QKV: wave wid owns tokens wid*32..+31; out frags j: {q0,q1,k0,k1,v0,v1} ----
    f32x4 qk[2][6];
    #pragma unroll
    for (int i = 0; i < 2; i++)
        #pragma unroll
        for (int jj = 0; jj < 6; jj++) qk[i][jj] = (f32x4){0.f, 0.f, 0.f, 0.f};
    #pragma unroll
    for (int kf = 0; kf < 6; kf++) {
        bf16x8 a0 = *(const bf16x8*)&xw_s[(wid * 32 + li) * 200 + kf * 32 + g * 8];
        bf16x8 a1 = *(const bf16x8*)&xw_s[(wid * 32 + 16 + li) * 200 + kf * 32 + g * 8];
        __builtin_amdgcn_s_setprio(1);
        #pragma unroll
        for (int jj = 0; jj < 6; jj++) {
            int nf = (jj >> 1) * 12 + 2 * h + (jj & 1);
            bf16x8 bw = *(const bf16x8*)&qkvpk[(((long)nf * 6 + kf) * 64 + lane) * 8];
            qk[0][jj] = __builtin_amdgcn_mfma_f32_16x16x32_bf16(a0, bw, qk[0][jj], 0, 0, 0);
            qk[1][jj] = __builtin_amdgcn_mfma_f32_16x16x32_bf16(a1, bw, qk[1][jj], 0, 0, 0);
        }
        __builtin_amdgcn_s_setprio(0);
    }
    // scatter q/k/v into LDS (col=li, row=token g*4+r per C/D layout)
    #pragma unroll
    for (int mf = 0; mf < 2; mf++) {
        int tokb = wid * 32 + mf * 16 + g * 4;
        #pragma unroll
        for (int r = 0; r < 4; r++) {
            int tok = tokb + r;
            q_s[tok * 36 + li]          = f2bf(qk[mf][0][r]);
            q_s[tok * 36 + 16 + li]     = f2bf(qk[mf][1][r]);
            k_s[tok * 36 + li]          = f2bf(qk[mf][2][r]);
            k_s[tok * 36 + 16 + li]     = f2bf(qk[mf][3][r]);
            vt_s[li * 136 + tok]        = f2bf(qk[mf][4][r]);
            vt_s[(16 + li) * 136 + tok] = f2bf(qk[mf][5][r]);
        }
    }
    __syncthreads();   // all xw_s reads done; p_s may overlay from here on

    f32x4 s[2][8];
    #pragma unroll
    for (int i = 0; i < 2; i++)
        #pragma unroll
        for (int jj = 0; jj < 8; jj++) s[i][jj] = (f32x4){0.f, 0.f, 0.f, 0.f};
    bf16x8 qa[2];
    #pragma unroll
    for (int fm = 0; fm < 2; fm++)
        qa[fm] = *(const bf16x8*)&q_s[(wid * 32 + fm * 16 + li) * 36 + g * 8];
    __builtin_amdgcn_s_setprio(1);
    #pragma unroll
    for (int fn = 0; fn < 8; fn++) {
        bf16x8 kb = *(const bf16x8*)&k_s[(fn * 16 + li) * 36 + g * 8];
        s[0][fn] = __builtin_amdgcn_mfma_f32_16x16x32_bf16(qa[0], kb, s[0][fn], 0, 0, 0);
        s[1][fn] = __builtin_amdgcn_mfma_f32_16x16x32_bf16(qa[1], kb, s[1][fn], 0, 0, 0);
    }
    __builtin_amdgcn_s_setprio(0);
    __syncthreads();

    #pragma unroll
    for (int fm = 0; fm < 2; fm++) {
        #pragma unroll
        for (int r = 0; r < 4; r++) {
            int i = wid * 32 + fm * 16 + g * 4 + r;
            const float4 b0 = *(const float4*)&bm[i * 128 + li * 8];
            const float4 b1 = *(const float4*)&bm[i * 128 + li * 8 + 4];
            float vals[8];
            vals[0] = s[fm][0][r] + b0.x; vals[1] = s[fm][1][r] + b0.y;
            vals[2] = s[fm][2][r] + b0.z; vals[3] = s[fm][3][r] + b0.w;
            vals[4] = s[fm][4][r] + b1.x; vals[5] = s[fm][5][r] + b1.y;
            vals[6] = s[fm][6][r] + b1.z; vals[7] = s[fm][7][r] + b1.w;
            float mx = fmaxf(fmaxf(fmaxf(vals[0], vals[1]), fmaxf(vals[2], vals[3])),
                             fmaxf(fmaxf(vals[4], vals[5]), fmaxf(vals[6], vals[7])));
            #pragma unroll
            for (int m = 1; m < 16; m <<= 1) mx = fmaxf(mx, __shfl_xor(mx, m, 16));
            float sum = 0.f;
            #pragma unroll
            for (int fn = 0; fn < 8; fn++) { vals[fn] = __expf(vals[fn] - mx); sum += vals[fn]; }
            #pragma unroll
            for (int m = 1; m < 16; m <<= 1) sum += __shfl_xor(sum, m, 16);
            float inv = __builtin_amdgcn_rcpf(sum);
            #pragma unroll
            for (int fn = 0; fn < 8; fn++)
                p_s[i * 132 + fn * 16 + li] = f2bf(vals[fn] * inv);
        }
    }

    f32x4 o[2][2];
    #pragma unroll
    for (int i = 0; i < 2; i++)
        #pragma unroll
        for (int jj = 0; jj < 2; jj++) o[i][jj] = (f32x4){0.f, 0.f, 0.f, 0.f};
    __builtin_amdgcn_s_setprio(1);
    #pragma unroll
    for (int ks = 0; ks < 4; ks++) {
        bf16x8 pa[2];
        #pragma unroll
        for (int fm = 0; fm < 2; fm++)
            pa[fm] = *(const bf16x8*)&p_s[(wid * 32 + fm * 16 + li) * 132 + ks * 32 + g * 8];
        #pragma unroll
        for (int fn = 0; fn < 2; fn++) {
            bf16x8 vb = *(const bf16x8*)&vt_s[(fn * 16 + li) * 136 + ks * 32 + g * 8];
            o[0][fn] = __builtin_amdgcn_mfma_f32_16x16x32_bf16(pa[0], vb, o[0][fn], 0, 0, 0);
            o[1][fn] = __builtin_amdgcn_mfma_f32_16x16x32_bf16(pa[1], vb, o[1][fn], 0, 0, 0);
        }
    }
    __builtin_amdgcn_s_setprio(0);

    unsigned short* op = attnout + (long)w * 128 * 192 + h * 32;
    #pragma unroll
    for (int fm = 0; fm < 2; fm++) {
        #pragma unroll
        for (int fn = 0; fn < 2; fn++) {
            #pragma unroll
            for (int r = 0; r < 4; r++) {
                int n = wid * 32 + fm * 16 + g * 4 + r;
                op[(long)n * 192 + fn * 16 + li] = f2bf(o[fm][fn][r]);
            }
        }
    }
}

// ---------------- host ----------------
extern "C" void kernel_launch(void* const* d_in, const int* in_sizes, int n_in,
                              void* d_out, int out_size, void* d_ws, size_t ws_size,
                              hipStream_t stream) {
    const float* x   = (const float*)d_in[0];
    const float* g1  = (const float*)d_in[1];
    const float* b1  = (const float*)d_in[2];
    const float* Wq  = (const float*)d_in[3];
    const float* Wkv = (const float*)d_in[4];
    const float* rpb = (const float*)d_in[5];
    const float* Wp  = (const float*)d_in[6];
    const float* bp  = (const float*)d_in[7];
    const float* g2  = (const float*)d_in[8];
    const float* b2  = (const float*)d_in[9];
    const float* Wf1 = (const float*)d_in[10];
    const float* bf1 = (const float*)d_in[11];
    const float* Wf2 = (const float*)d_in[12];
    const float* bf2 = (const float*)d_in[13];
    float* out = (float*)d_out;
    char* ws = (char*)d_ws;

    unsigned short* wpk  = (unsigned short*)ws;               // 884736 B
    float* bmt           = (float*)(ws + 917504);             // 3145728 B -> ends 4063232
    unsigned short* xw   = (unsigned short*)(ws + 4194304);   // 25165824 B -> ends 29360128
    unsigned short* attb = (unsigned short*)(ws + 29360128);  // 25165824 B -> ends 54525952
    unsigned short* x1b  = (unsigned short*)(ws + 54525952);  // 25165824 B bf16 -> ends 79691776

    const unsigned short* qkvpk = wpk;
    const unsigned short* wppk  = wpk + 110592;
    const unsigned short* wf1pk = wpk + 147456;
    const unsigned short* wf2pk = wpk + 294912;

    k_pack<<<216, 256, 0, stream>>>(Wq, Wkv, Wp, Wf1, Wf2, wpk);
    k_bmt<<<3072, 256, 0, stream>>>(rpb, bmt);
    k_ln<<<16384, 256, 0, stream>>>(x, g1, b1, xw);
    k_attn<<<3072, 256, 0, stream>>>(xw, qkvpk, bmt, attb);
    k_gemm<1><<<dim3(3, 256), 256, 0, stream>>>(attb, wppk, 192, bp, x, x1b);
    k_mlp<<<1024, 512, 0, stream>>>(x1b, g2, b2, wf1pk, wf2pk, bf1, bf2, out);
}